// Round 13
// baseline (843.568 us; speedup 1.0000x reference)
//
#include <hip/hip_runtime.h>
#include <math.h>

typedef unsigned char  u8;
typedef unsigned short u16;
typedef unsigned int   u32;
typedef __attribute__((ext_vector_type(8))) unsigned short ushort8;
typedef __attribute__((ext_vector_type(4))) unsigned short ushort4v;
typedef __attribute__((ext_vector_type(8))) short short8v;   // 8 bf16 (4 VGPRs)
typedef __attribute__((ext_vector_type(4))) float f32x4;
typedef __attribute__((ext_vector_type(2))) float f32x2;

__device__ __forceinline__ float gelu_f(float x) {
    const float c = 0.7978845608028654f;   // sqrt(2/pi)
    float x3 = x * x * x;
    float t = tanhf(c * (x + 0.044715f * x3));
    return 0.5f * x * (1.0f + t);
}

__device__ __forceinline__ u16 f2b(float f) {
    u32 u = __float_as_uint(f);
    return (u16)((u + 0x7FFFu + ((u >> 16) & 1u)) >> 16);
}
__device__ __forceinline__ float b2f(u16 u) {
    return __uint_as_float(((u32)u) << 16);
}

// fp8 e4m3fn software fallback
__device__ __forceinline__ u32 f2fp8_sw(float f) {
    u32 u = __float_as_uint(f);
    u32 s = (u >> 31) << 7;
    float af = fabsf(f);
    if (af >= 448.0f) return s | 0x7E;
    if (af < 0.015625f) {
        int m = __float2int_rn(af * 512.0f);
        if (m >= 8) return s | 0x08;
        return s | (u32)m;
    }
    u32 a = __float_as_uint(af);
    u32 r = a + 0xFFFFFu + ((a >> 20) & 1u);
    int e8 = (int)(r >> 23) - 120;
    u32 m3 = (r >> 20) & 7u;
    if (e8 >= 16) return s | 0x7E;
    return s | ((u32)e8 << 3) | m3;
}
__device__ __forceinline__ float fp8d_sw(u32 b) {
    u32 lo = b & 0x7Fu;
    u32 nb = (lo << 20) + 0x3C000000u;
    float n = __uint_as_float(nb | ((b & 0x80u) << 24));
    float sub = (float)(b & 7u) * 0.001953125f;
    sub = (b & 0x80u) ? -sub : sub;
    return (lo & 0x78u) ? n : sub;
}
__device__ __forceinline__ u8 f2fp8(float v) {
#if __has_builtin(__builtin_amdgcn_cvt_pk_fp8_f32)
    return (u8)(__builtin_amdgcn_cvt_pk_fp8_f32(v, v, 0, false) & 0xFF);
#else
    return (u8)f2fp8_sw(v);
#endif
}
__device__ __forceinline__ f32x2 kvdec(u32 pair) {
#if __has_builtin(__builtin_amdgcn_cvt_pk_f32_fp8)
    return __builtin_amdgcn_cvt_pk_f32_fp8((int)pair, false);
#else
    f32x2 r;
    r[0] = fp8d_sw(pair & 0xFF);
    r[1] = fp8d_sw((pair >> 8) & 0xFF);
    return r;
#endif
}

__device__ __forceinline__ void split_bf16(float f, u16& h, u16& l) {
    u32 u = __float_as_uint(f);
    u32 r = (u + 0x7FFFu + ((u >> 16) & 1u)) >> 16;
    h = (u16)r;
    float hf = __uint_as_float(r << 16);
    float d = f - hf;
    u32 u2 = __float_as_uint(d);
    l = (u16)((u2 + 0x7FFFu + ((u2 >> 16) & 1u)) >> 16);
}

// bijective XCD-chunked swizzle (m204)
__device__ __forceinline__ int xcd_swz(int orig, int nwg) {
    int q8 = nwg >> 3, r8 = nwg & 7;
    int xcd = orig & 7, ii = orig >> 3;
    return (xcd < r8 ? xcd * (q8 + 1) : r8 * (q8 + 1) + (xcd - r8) * q8) + ii;
}

// ---------------------------------------------------------------------------
__global__ __launch_bounds__(256) void zero2_i32(int* __restrict__ a, int na,
                                                 int* __restrict__ b, int nb) {
    int i = blockIdx.x * 256 + threadIdx.x;
    if (i < na) a[i] = 0;
    else if (i - na < nb) b[i - na] = 0;
}

// ---------------------------------------------------------------------------
// Weight pre-pass: transpose [K][N] f32 -> [N][K] split bf16 hi/lo
// ---------------------------------------------------------------------------
struct TEntry { const float* src; u16* dh; u16* dl; int K; int N; };
struct TDesc  { TEntry e[29]; };

__global__ __launch_bounds__(256) void transpose_split(TDesc desc) {
    __shared__ float tile[32][33];
    TEntry en = desc.e[blockIdx.y];
    int tk = en.K >> 5, tn = en.N >> 5;
    int bx = blockIdx.x;
    if (bx >= tk * tn) return;
    int k0 = (bx % tk) * 32, n0 = (bx / tk) * 32;
    int tx = threadIdx.x & 31, ty = threadIdx.x >> 5;
    #pragma unroll
    for (int yy = 0; yy < 32; yy += 8)
        tile[ty + yy][tx] = en.src[(size_t)(k0 + ty + yy) * en.N + (n0 + tx)];
    __syncthreads();
    #pragma unroll
    for (int yy = 0; yy < 32; yy += 8) {
        int n = n0 + ty + yy, k = k0 + tx;
        float f = tile[tx][ty + yy];
        u16 h, l;
        split_bf16(f, h, l);
        en.dh[(size_t)n * en.K + k] = h;
        en.dl[(size_t)n * en.K + k] = l;
    }
}

// ---------------------------------------------------------------------------
// RBF lookup tables: packed bf16 pairs (val[k], val[k+1]) per u32.
// 4097 entries per layer; entry 4096 = (0,0) (cutoff).
// ---------------------------------------------------------------------------
__device__ __forceinline__ float rbf_val(int k, const float* __restrict__ Wrbf_l, int m) {
    const float PI = 3.14159265358979323846f;
    float d = fmaxf((float)k * (6.0f / 4096.0f), 1e-9f);
    float th = d * (PI / 6.0f);
    float s1, c1;
    __sincosf(th, &s1, &c1);
    float env = (d < 6.0f) ? (0.5f * c1 + 0.5f) : 0.0f;
    float invd = 1.0f / d;
    float two_c = 2.0f * c1;
    float sp = 0.f, sc = s1, dot = 0.f;
    #pragma unroll
    for (int r = 0; r < 32; ++r) {
        dot = fmaf(sc, Wrbf_l[r * 128 + m], dot);
        float sn = fmaf(two_c, sc, -sp);
        sp = sc; sc = sn;
    }
    return dot * invd * env;
}

__global__ __launch_bounds__(128) void build_rbf_table(
    const float* __restrict__ W_rbf, u32* __restrict__ table)
{
    int k = blockIdx.x, l = blockIdx.y, m = threadIdx.x;
    const float* Wrbf_l = W_rbf + (size_t)l * 32 * 128;
    float v0 = rbf_val(k, Wrbf_l, m);
    float v1 = rbf_val(k + 1, Wrbf_l, m);
    table[((size_t)l * 4097 + k) * 128 + m] = (u32)f2b(v0) | ((u32)f2b(v1) << 16);
}

// ---------------------------------------------------------------------------
// MFMA GEMM, 1D swizzled grid. A bf16 [M][K]; BH (+BL) transposed bf16 [N][K].
// OMODE: 0 f32 out (ACCUM f32 +=), 1 bf16 out, 2 bf16 out + bf16 accum,
//        3 qkv mixed (Q bf16 / K,V fp8 pairs)
// ---------------------------------------------------------------------------
template<int OMODE, bool ACCUM, bool BIAS, bool DOGELU, bool SPLITB>
__global__ __launch_bounds__(256) void mfma_gemm(
    const u16* __restrict__ A, const u16* __restrict__ BH,
    const u16* __restrict__ BL, const float* __restrict__ bias,
    void* __restrict__ Cv, void* __restrict__ Cv2,
    int Mrows, int K, int Nc, int gx)
{
    constexpr bool STAGE_OUT = (OMODE == 1 || OMODE == 2);
    constexpr int MAIN_B = 128 * 40 * 2 * (SPLITB ? 3 : 2);
    constexpr int OUT_B  = STAGE_OUT ? 128 * 136 * 2 : 0;
    constexpr int SMEM_B = (MAIN_B > OUT_B) ? MAIN_B : OUT_B;
    __shared__ __align__(16) char smem[SMEM_B];
    u16 (*sA)[40]  = (u16(*)[40])smem;
    u16 (*sBh)[40] = (u16(*)[40])(smem + 128 * 40 * 2);
    u16 (*sBl)[40] = (u16(*)[40])(smem + 2 * 128 * 40 * 2);
    u16 (*sOut)[136] = (u16(*)[136])smem;

    const int wg = xcd_swz(blockIdx.x, gridDim.x);
    const int r0 = (wg / gx) * 128, c0 = (wg % gx) * 128;

    const int t = threadIdx.x;
    const int lane = t & 63, wid = t >> 6;
    const int wr = (wid >> 1) * 64, wc = (wid & 1) * 64;

    f32x4 acc[4][4] = {};

    const int srow = t >> 1;
    const int skc  = (t & 1) * 16;

    for (int k0 = 0; k0 < K; k0 += 32) {
        {
            int gr = r0 + srow;
            ushort8 h0, h1;
            if (gr < Mrows) {
                const u16* p = A + (size_t)gr * K + (k0 + skc);
                h0 = *(const ushort8*)p;
                h1 = *(const ushort8*)(p + 8);
            } else {
                #pragma unroll
                for (int j = 0; j < 8; ++j) { h0[j] = 0; h1[j] = 0; }
            }
            *(ushort8*)&sA[srow][skc]     = h0;
            *(ushort8*)&sA[srow][skc + 8] = h1;
        }
        {
            int cg = c0 + srow;
            const u16* ph = BH + (size_t)cg * K + (k0 + skc);
            *(ushort8*)&sBh[srow][skc]     = *(const ushort8*)(ph);
            *(ushort8*)&sBh[srow][skc + 8] = *(const ushort8*)(ph + 8);
            if constexpr (SPLITB) {
                const u16* pl = BL + (size_t)cg * K + (k0 + skc);
                *(ushort8*)&sBl[srow][skc]     = *(const ushort8*)(pl);
                *(ushort8*)&sBl[srow][skc + 8] = *(const ushort8*)(pl + 8);
            }
        }
        __syncthreads();

        const int arow = wr + (lane & 15);
        const int koff = (lane >> 4) * 8;
        short8v ah[4];
        #pragma unroll
        for (int fr = 0; fr < 4; ++fr)
            ah[fr] = *(const short8v*)&sA[arow + fr * 16][koff];
        #pragma unroll
        for (int fc = 0; fc < 4; ++fc) {
            int bcol = wc + fc * 16 + (lane & 15);
            short8v bh = *(const short8v*)&sBh[bcol][koff];
            #pragma unroll
            for (int fr = 0; fr < 4; ++fr)
                acc[fr][fc] = __builtin_amdgcn_mfma_f32_16x16x32_bf16(ah[fr], bh, acc[fr][fc], 0, 0, 0);
            if constexpr (SPLITB) {
                short8v bl = *(const short8v*)&sBl[bcol][koff];
                #pragma unroll
                for (int fr = 0; fr < 4; ++fr)
                    acc[fr][fc] = __builtin_amdgcn_mfma_f32_16x16x32_bf16(ah[fr], bl, acc[fr][fc], 0, 0, 0);
            }
        }
        __syncthreads();
    }

    if constexpr (STAGE_OUT) {
        #pragma unroll
        for (int fr = 0; fr < 4; ++fr) {
            int rbase = wr + fr * 16 + (lane >> 4) * 4;
            #pragma unroll
            for (int fc = 0; fc < 4; ++fc) {
                int col = wc + fc * 16 + (lane & 15);
                #pragma unroll
                for (int reg = 0; reg < 4; ++reg) {
                    float v = acc[fr][fc][reg];
                    if (BIAS)   v += bias[c0 + col];
                    if (DOGELU) v = gelu_f(v);
                    sOut[rbase + reg][col] = f2b(v);
                }
            }
        }
        __syncthreads();
        #pragma unroll
        for (int p = 0; p < 4; ++p) {
            int row = p * 32 + (t >> 3);
            int cch = (t & 7) * 16;
            int gr = r0 + row;
            if (gr < Mrows) {
                u16* gp = (u16*)Cv + (size_t)gr * Nc + c0 + cch;
                ushort8 v0 = *(ushort8*)&sOut[row][cch];
                ushort8 v1 = *(ushort8*)&sOut[row][cch + 8];
                if (OMODE == 2) {
                    ushort8 o0 = *(const ushort8*)gp;
                    ushort8 o1 = *(const ushort8*)(gp + 8);
                    #pragma unroll
                    for (int j = 0; j < 8; ++j) {
                        v0[j] = f2b(b2f(v0[j]) + b2f(o0[j]));
                        v1[j] = f2b(b2f(v1[j]) + b2f(o1[j]));
                    }
                }
                *(ushort8*)gp       = v0;
                *(ushort8*)(gp + 8) = v1;
            }
        }
    } else {
        #pragma unroll
        for (int fr = 0; fr < 4; ++fr) {
            int rbase = r0 + wr + fr * 16 + (lane >> 4) * 4;
            #pragma unroll
            for (int fc = 0; fc < 4; ++fc) {
                int col = c0 + wc + fc * 16 + (lane & 15);
                #pragma unroll
                for (int reg = 0; reg < 4; ++reg) {
                    int gr = rbase + reg;
                    if (gr >= Mrows) continue;
                    float v = acc[fr][fc][reg];
                    if (BIAS)   v += bias[col];
                    if (DOGELU) v = gelu_f(v);
                    if (OMODE == 0) {
                        float* pc = (float*)Cv + (size_t)gr * Nc + col;
                        if (ACCUM) v += *pc;
                        *pc = v;
                    } else {   // OMODE 3: qkv mixed
                        if (col < 128)
                            ((u16*)Cv)[(size_t)gr * 128 + col] = f2b(v);
                        else if (col < 256)
                            ((u8*)Cv2)[(size_t)gr * 256 + (col - 128) * 2] = f2fp8(v);
                        else
                            ((u8*)Cv2)[(size_t)gr * 256 + (col - 256) * 2 + 1] = f2fp8(v);
                    }
                }
            }
        }
    }
}

// ---------------------------------------------------------------------------
// Fused MLP: b2 = gelu(gelu(msg@Wmsg) @ Wnd + bnd).  BM=128, BN=256, 8 waves.
// ---------------------------------------------------------------------------
__global__ __launch_bounds__(512) void mlp_kernel(
    const u16* __restrict__ msg, const u16* __restrict__ Wmsg,
    const u16* __restrict__ WndH, const u16* __restrict__ WndL,
    const float* __restrict__ bnd, u16* __restrict__ b2out, int Mrows)
{
    __shared__ __align__(16) u16 b1[128][264];
    __shared__ __align__(16) char sbuf[256 * 40 * 2 * 2];
    u16 (*sA)[40]   = (u16(*)[40])sbuf;
    u16 (*sB)[40]   = (u16(*)[40])(sbuf + 128 * 40 * 2);
    u16 (*sBh)[40]  = (u16(*)[40])sbuf;
    u16 (*sBl)[40]  = (u16(*)[40])(sbuf + 256 * 40 * 2);
    u16 (*sOut)[136] = (u16(*)[136])sbuf;

    const int r0 = xcd_swz(blockIdx.x, gridDim.x) * 128;
    const int t = threadIdx.x;
    const int lane = t & 63, wid = t >> 6;
    const int wr = (wid >> 2) * 64, wc = (wid & 3) * 64;

    f32x4 acc[4][4] = {};
    const int srowA = t >> 2, skcA = (t & 3) * 8;
    const int srowB = t >> 1, skcB = (t & 1) * 16;

    for (int k0 = 0; k0 < 128; k0 += 32) {
        {
            int gr = r0 + srowA;
            ushort8 h0;
            #pragma unroll
            for (int j = 0; j < 8; ++j) h0[j] = 0;
            if (gr < Mrows) h0 = *(const ushort8*)(msg + (size_t)gr * 128 + k0 + skcA);
            *(ushort8*)&sA[srowA][skcA] = h0;
        }
        {
            const u16* p = Wmsg + (size_t)srowB * 128 + k0 + skcB;
            *(ushort8*)&sB[srowB][skcB]     = *(const ushort8*)p;
            *(ushort8*)&sB[srowB][skcB + 8] = *(const ushort8*)(p + 8);
        }
        __syncthreads();
        const int arow = wr + (lane & 15);
        const int koff = (lane >> 4) * 8;
        short8v ah[4];
        #pragma unroll
        for (int fr = 0; fr < 4; ++fr)
            ah[fr] = *(const short8v*)&sA[arow + fr * 16][koff];
        #pragma unroll
        for (int fc = 0; fc < 4; ++fc) {
            int bcol = wc + fc * 16 + (lane & 15);
            short8v bh = *(const short8v*)&sB[bcol][koff];
            #pragma unroll
            for (int fr = 0; fr < 4; ++fr)
                acc[fr][fc] = __builtin_amdgcn_mfma_f32_16x16x32_bf16(ah[fr], bh, acc[fr][fc], 0, 0, 0);
        }
        __syncthreads();
    }
    #pragma unroll
    for (int fr = 0; fr < 4; ++fr) {
        int rbase = wr + fr * 16 + (lane >> 4) * 4;
        #pragma unroll
        for (int fc = 0; fc < 4; ++fc) {
            int col = wc + fc * 16 + (lane & 15);
            #pragma unroll
            for (int reg = 0; reg < 4; ++reg) {
                b1[rbase + reg][col] = f2b(gelu_f(acc[fr][fc][reg]));
                acc[fr][fc][reg] = 0.0f;
            }
        }
    }
    __syncthreads();

    for (int k0 = 0; k0 < 256; k0 += 32) {
        {
            const u16* ph = WndH + (size_t)srowB * 256 + k0 + skcB;
            const u16* pl = WndL + (size_t)srowB * 256 + k0 + skcB;
            *(ushort8*)&sBh[srowB][skcB]     = *(const ushort8*)ph;
            *(ushort8*)&sBh[srowB][skcB + 8] = *(const ushort8*)(ph + 8);
            *(ushort8*)&sBl[srowB][skcB]     = *(const ushort8*)pl;
            *(ushort8*)&sBl[srowB][skcB + 8] = *(const ushort8*)(pl + 8);
        }
        __syncthreads();
        const int arow = wr + (lane & 15);
        const int koff = (lane >> 4) * 8;
        short8v ah[4];
        #pragma unroll
        for (int fr = 0; fr < 4; ++fr)
            ah[fr] = *(const short8v*)&b1[arow + fr * 16][k0 + koff];
        #pragma unroll
        for (int fc = 0; fc < 4; ++fc) {
            int bcol = wc + fc * 16 + (lane & 15);
            short8v bh = *(const short8v*)&sBh[bcol][koff];
            short8v bl = *(const short8v*)&sBl[bcol][koff];
            #pragma unroll
            for (int fr = 0; fr < 4; ++fr) {
                acc[fr][fc] = __builtin_amdgcn_mfma_f32_16x16x32_bf16(ah[fr], bh, acc[fr][fc], 0, 0, 0);
                acc[fr][fc] = __builtin_amdgcn_mfma_f32_16x16x32_bf16(ah[fr], bl, acc[fr][fc], 0, 0, 0);
            }
        }
        __syncthreads();
    }

    #pragma unroll
    for (int fr = 0; fr < 4; ++fr) {
        int rbase = wr + fr * 16 + (lane >> 4) * 4;
        #pragma unroll
        for (int fc = 0; fc < 4; ++fc) {
            int col = wc + fc * 16 + (lane & 15);
            #pragma unroll
            for (int reg = 0; reg < 4; ++reg)
                sOut[rbase + reg][col] = f2b(gelu_f(acc[fr][fc][reg] + bnd[col]));
        }
    }
    __syncthreads();
    #pragma unroll
    for (int p = 0; p < 2; ++p) {
        int row = p * 64 + (t >> 3);
        int cch = (t & 7) * 16;
        int gr = r0 + row;
        if (gr < Mrows) {
            u16* gp = b2out + (size_t)gr * 256 + cch;
            *(ushort8*)gp       = *(ushort8*)&sOut[row][cch];
            *(ushort8*)(gp + 8) = *(ushort8*)&sOut[row][cch + 8];
        }
    }
}

// ---------------------------------------------------------------------------
// Fused vs-GEMM + LayerNorm, vnorm inline.
// ---------------------------------------------------------------------------
__global__ __launch_bounds__(512) void vs_ln_kernel(
    const u16* __restrict__ vf, const u16* __restrict__ BH,
    const u16* __restrict__ BL, const u16* __restrict__ b2,
    const float* __restrict__ gamma_l, u16* __restrict__ h16, int Mrows)
{
    __shared__ __align__(16) u16 sA [128][40];
    __shared__ __align__(16) u16 sBh[256][40];
    __shared__ __align__(16) u16 sBl[256][40];
    __shared__ float sSum[128][4];
    __shared__ float sSq [128][4];

    const int r0 = blockIdx.x * 128;
    const int t = threadIdx.x;
    const int lane = t & 63, wid = t >> 6;
    const int wr = (wid >> 2) * 64, wc = (wid & 3) * 64;

    f32x4 acc[4][4] = {};
    const int K = 256;
    const int srow = t >> 2;
    const int skc  = (t & 3) * 8;

    for (int k0 = 0; k0 < K; k0 += 32) {
        {
            int gr = r0 + srow;
            ushort8 h0;
            #pragma unroll
            for (int j = 0; j < 8; ++j) h0[j] = 0;
            if (gr < Mrows) {
                const u16* base = vf + ((size_t)gr * 3) * 256 + k0 + skc;
                ushort8 v0 = *(const ushort8*)(base);
                ushort8 v1 = *(const ushort8*)(base + 256);
                ushort8 v2 = *(const ushort8*)(base + 512);
                #pragma unroll
                for (int j = 0; j < 8; ++j) {
                    float a = b2f(v0[j]), b = b2f(v1[j]), c = b2f(v2[j]);
                    h0[j] = f2b(sqrtf(a * a + b * b + c * c + 1e-8f));
                }
            }
            *(ushort8*)&sA[srow][skc] = h0;
        }
        {
            *(ushort8*)&sBh[srow][skc]       = *(const ushort8*)(BH + (size_t)srow * K + k0 + skc);
            *(ushort8*)&sBh[srow + 128][skc] = *(const ushort8*)(BH + (size_t)(srow + 128) * K + k0 + skc);
            *(ushort8*)&sBl[srow][skc]       = *(const ushort8*)(BL + (size_t)srow * K + k0 + skc);
            *(ushort8*)&sBl[srow + 128][skc] = *(const ushort8*)(BL + (size_t)(srow + 128) * K + k0 + skc);
        }
        __syncthreads();

        const int arow = wr + (lane & 15);
        const int koff = (lane >> 4) * 8;
        short8v ah[4];
        #pragma unroll
        for (int fr = 0; fr < 4; ++fr)
            ah[fr] = *(const short8v*)&sA[arow + fr * 16][koff];
        #pragma unroll
        for (int fc = 0; fc < 4; ++fc) {
            int bcol = wc + fc * 16 + (lane & 15);
            short8v bh = *(const short8v*)&sBh[bcol][koff];
            short8v bl = *(const short8v*)&sBl[bcol][koff];
            #pragma unroll
            for (int fr = 0; fr < 4; ++fr) {
                acc[fr][fc] = __builtin_amdgcn_mfma_f32_16x16x32_bf16(ah[fr], bh, acc[fr][fc], 0, 0, 0);
                acc[fr][fc] = __builtin_amdgcn_mfma_f32_16x16x32_bf16(ah[fr], bl, acc[fr][fc], 0, 0, 0);
            }
        }
        __syncthreads();
    }

    float psum[4][4] = {}, psq[4][4] = {};
    #pragma unroll
    for (int fr = 0; fr < 4; ++fr) {
        #pragma unroll
        for (int fc = 0; fc < 4; ++fc) {
            int col = wc + fc * 16 + (lane & 15);
            #pragma unroll
            for (int reg = 0; reg < 4; ++reg) {
                int gr = r0 + wr + fr * 16 + (lane >> 4) * 4 + reg;
                float x = 0.f;
                if (gr < Mrows) {
                    size_t ix = (size_t)gr * 256 + col;
                    x = acc[fr][fc][reg] + b2f(b2[ix]) + b2f(h16[ix]);
                }
                acc[fr][fc][reg] = x;
                psum[fr][reg] += x;
                psq[fr][reg]  = fmaf(x, x, psq[fr][reg]);
            }
        }
    }
    #pragma unroll
    for (int fr = 0; fr < 4; ++fr) {
        #pragma unroll
        for (int reg = 0; reg < 4; ++reg) {
            float s = psum[fr][reg], sq = psq[fr][reg];
            #pragma unroll
            for (int off = 8; off; off >>= 1) {
                s  += __shfl_xor(s, off);
                sq += __shfl_xor(sq, off);
            }
            psum[fr][reg] = s; psq[fr][reg] = sq;
        }
    }
    if ((lane & 15) == 0) {
        int qg = lane >> 4;
        #pragma unroll
        for (int fr = 0; fr < 4; ++fr) {
            #pragma unroll
            for (int reg = 0; reg < 4; ++reg) {
                int row = wr + fr * 16 + qg * 4 + reg;
                sSum[row][wc >> 6] = psum[fr][reg];
                sSq [row][wc >> 6] = psq[fr][reg];
            }
        }
    }
    __syncthreads();
    #pragma unroll
    for (int fr = 0; fr < 4; ++fr) {
        #pragma unroll
        for (int reg = 0; reg < 4; ++reg) {
            int row = wr + fr * 16 + (lane >> 4) * 4 + reg;
            int gr = r0 + row;
            if (gr >= Mrows) continue;
            float S = sSum[row][0] + sSum[row][1] + sSum[row][2] + sSum[row][3];
            float Q = sSq[row][0] + sSq[row][1] + sSq[row][2] + sSq[row][3];
            float mu = S * (1.0f / 256.0f);
            float var = fmaxf(Q * (1.0f / 256.0f) - mu * mu, 0.0f);
            float rs = rsqrtf(var + 1e-5f);
            #pragma unroll
            for (int fc = 0; fc < 4; ++fc) {
                int col = wc + fc * 16 + (lane & 15);
                float y = (acc[fr][fc][reg] - mu) * rs * gamma_l[col];
                h16[(size_t)gr * 256 + col] = f2b(y);
            }
        }
    }
}

// ---------------------------------------------------------------------------
// Setup: degree + graph histograms (one kernel)
// ---------------------------------------------------------------------------
__global__ __launch_bounds__(256) void setup_hist(
    const int* __restrict__ ei, const int* __restrict__ batch, int E_, int Nn,
    int* __restrict__ deg, int* __restrict__ gcnt)
{
    int x = blockIdx.x * 256 + threadIdx.x;
    if (x < E_) atomicAdd(&deg[ei[E_ + x]], 1);
    if (x < Nn) atomicAdd(&gcnt[batch[x]], 1);
}

// two scans in one launch
__global__ __launch_bounds__(1024) void scan2_kernel(
    const int* __restrict__ cntA, int nA, int* __restrict__ outA, int* __restrict__ curA,
    const int* __restrict__ cntB, int nB, int* __restrict__ outB)
{
    __shared__ int part[1024];
    const int* cnt = (blockIdx.x == 0) ? cntA : cntB;
    int n          = (blockIdx.x == 0) ? nA : nB;
    int* out       = (blockIdx.x == 0) ? outA : outB;
    int* cursor    = (blockIdx.x == 0) ? curA : (int*)nullptr;
    int t = threadIdx.x;
    int chunk = (n + 1023) / 1024;
    int base = t * chunk;
    int s = 0;
    for (int k = 0; k < chunk; ++k) { int i = base + k; if (i < n) s += cnt[i]; }
    part[t] = s;
    __syncthreads();
    for (int off = 1; off < 1024; off <<= 1) {
        int u = (t >= off) ? part[t - off] : 0;
        __syncthreads();
        part[t] += u;
        __syncthreads();
    }
    int run = part[t] - s;
    for (int k = 0; k < chunk; ++k) {
        int i = base + k;
        if (i < n) {
            out[i] = run;
            if (cursor) cursor[i] = run;
            run += cnt[i];
        }
    }
    if (t == 1023) out[n] = part[1023];
}

// scatter: edge record (src, dist f32, unit bf16x3) at CSR slot
__global__ void scatter_kernel(const int* __restrict__ ei, const float* __restrict__ pos,
                               int* __restrict__ cursor, int4* __restrict__ recs, int E_) {
    int e = blockIdx.x * 256 + threadIdx.x;
    if (e < E_) {
        int s = ei[e], dn = ei[E_ + e];
        int p = atomicAdd(&cursor[dn], 1);
        float dx = pos[s * 3 + 0] - pos[dn * 3 + 0];
        float dy = pos[s * 3 + 1] - pos[dn * 3 + 1];
        float dz = pos[s * 3 + 2] - pos[dn * 3 + 2];
        float d = sqrtf(dx * dx + dy * dy + dz * dz + 1e-12f);
        float invd = 1.0f / d;
        u32 uxy = (u32)f2b(dx * invd) | ((u32)f2b(dy * invd) << 16);
        u32 uz  = (u32)f2b(dz * invd);
        recs[p] = make_int4(s, __float_as_int(d), (int)uxy, (int)uz);
    }
}

// ---------------------------------------------------------------------------
// h init -> bf16
// ---------------------------------------------------------------------------
__global__ __launch_bounds__(256) void init_h_kernel(
    const int* __restrict__ z, const float* __restrict__ pos,
    const float* __restrict__ emb, const float* __restrict__ W_in,
    const float* __restrict__ b_in, u16* __restrict__ h16)
{
    int i = blockIdx.x, d = threadIdx.x;
    float acc = b_in[d];
    int zi = z[i];
    #pragma unroll 8
    for (int k = 0; k < 32; ++k)
        acc += emb[zi * 32 + k] * W_in[k * 256 + d];
    #pragma unroll
    for (int x = 0; x < 3; ++x)
        acc += pos[i * 3 + x] * W_in[(32 + x) * 256 + d];
    h16[(size_t)i * 256 + d] = f2b(acc);
}

// ---------------------------------------------------------------------------
// Per-dst-node edge attention, online softmax, 16 edges/iter.
// recs = (src, dist, unit bf16x3): one sequential 16B read per edge;
// kv8 fp8 pairs gathered; ew via packed bf16 table pair (one u32 load).
// ---------------------------------------------------------------------------
__global__ __launch_bounds__(128) void edge_attn_kernel(
    const int* __restrict__ rowptr, const int4* __restrict__ recs,
    const u16* __restrict__ q16, const u16* __restrict__ kv8,
    const u32* __restrict__ table_l,
    u16* __restrict__ msg, u16* __restrict__ U)
{
    int m = threadIdx.x;
    int i = blockIdx.x;

    int p0 = rowptr[i], p1 = rowptr[i + 1];
    float q = b2f(q16[(size_t)i * 128 + m]);
    float Mx = -1e30f, S = 0.f, am = 0.f, a0 = 0.f, a1 = 0.f, a2 = 0.f;
    const float iscale = 0.1767766952966369f;   // 1/sqrt(32)

    for (int p = p0; p < p1; p += 16) {
        int rem = p1 - p;
        int jj[16];
        float dd[16], ux[16], uy[16], uz[16];
        #pragma unroll
        for (int u = 0; u < 16; ++u) {
            int pp = p + (u < rem ? u : 0);
            int4 r = recs[pp];
            jj[u] = __builtin_amdgcn_readfirstlane(r.x);
            dd[u] = __int_as_float(__builtin_amdgcn_readfirstlane(r.y));
            u32 xy = (u32)__builtin_amdgcn_readfirstlane(r.z);
            u32 zz = (u32)__builtin_amdgcn_readfirstlane(r.w);
            ux[u] = b2f((u16)(xy & 0xFFFF));
            uy[u] = b2f((u16)(xy >> 16));
            uz[u] = b2f((u16)(zz & 0xFFFF));
        }
        u32 kv[16];
        #pragma unroll
        for (int u = 0; u < 16; ++u)
            kv[u] = kv8[(size_t)jj[u] * 128 + m];
        float ew[16];
        #pragma unroll
        for (int u = 0; u < 16; ++u) {
            float x = fminf(dd[u] * (4096.0f / 6.0f), 4096.0f);
            int b = (int)x;
            float tf = x - (float)b;
            u32 pr = table_l[(size_t)b * 128 + m];
            float f0 = b2f((u16)(pr & 0xFFFF));
            float f1 = b2f((u16)(pr >> 16));
            ew[u] = fmaf(tf, f1 - f0, f0);
        }
        float lg[16], vd[16];
        #pragma unroll
        for (int u = 0; u < 16; ++u) {
            f32x2 c = kvdec(kv[u]);
            vd[u] = c[1];
            float pr2 = q * c[0];
            #pragma unroll
            for (int off = 16; off; off >>= 1) pr2 += __shfl_xor(pr2, off);
            lg[u] = pr2 * iscale;
        }
        float Mb = Mx;
        #pragma unroll
        for (int u = 0; u < 16; ++u) Mb = fmaxf(Mb, lg[u]);
        float sc = __expf(Mx - Mb);
        float ws = 0.f, wvs = 0.f, wx = 0.f, wy = 0.f, wz = 0.f;
        #pragma unroll
        for (int u = 0; u < 16; ++u) {
            float w = (u < rem) ? __expf(lg[u] - Mb) : 0.f;
            float wv = w * vd[u] * ew[u];
            ws  += w;
            wvs += wv;
            wx = fmaf(wv, ux[u], wx);
            wy = fmaf(wv, uy[u], wy);
            wz = fmaf(wv, uz[u], wz);
        }
        S  = S  * sc + ws;
        am = am * sc + wvs;
        a0 = a0 * sc + wx;
        a1 = a1 * sc + wy;
        a2 = a2 * sc + wz;
        Mx = Mb;
    }
    float inv = 1.0f / (S + 1e-12f);
    msg[(size_t)i * 128 + m] = f2b(am * inv);
    U[((size_t)i * 3 + 0) * 128 + m] = f2b(a0 * inv);
    U[((size_t)i * 3 + 1) * 128 + m] = f2b(a1 * inv);
    U[((size_t)i * 3 + 2) * 128 + m] = f2b(a2 * inv);
}

// ---------------------------------------------------------------------------
// Graph pooling, wave-parallel (block = graph)
// ---------------------------------------------------------------------------
__global__ __launch_bounds__(256) void pool_kernel(
    const u16* __restrict__ h16, const float* __restrict__ w_att,
    const int* __restrict__ gptr, u16* __restrict__ pooled)
{
    __shared__ float sM[4], sS[4];
    __shared__ float sAcc[4][256];
    int g = blockIdx.x;
    int t = threadIdx.x, w = t >> 6, lane = t & 63;
    int c0 = lane * 4;
    int n0 = gptr[g], n1 = gptr[g + 1];
    float4 wa = *(const float4*)(w_att + c0);
    float M = -1e30f, S = 0.f, a0 = 0.f, a1 = 0.f, a2 = 0.f, a3 = 0.f;
    for (int i = n0 + w; i < n1; i += 4) {
        ushort4v hv = *(const ushort4v*)(h16 + (size_t)i * 256 + c0);
        float h0 = b2f(hv[0]), h1 = b2f(hv[1]), h2 = b2f(hv[2]), h3 = b2f(hv[3]);
        float p = h0 * wa.x + h1 * wa.y + h2 * wa.z + h3 * wa.w;
        #pragma unroll
        for (int off = 32; off; off >>= 1) p += __shfl_xor(p, off);
        float nM = fmaxf(M, p);
        float sc = __expf(M - nM), wg = __expf(p - nM);
        S = S * sc + wg;
        a0 = a0 * sc + wg * h0;
        a1 = a1 * sc + wg * h1;
        a2 = a2 * sc + wg * h2;
        a3 = a3 * sc + wg * h3;
        M = nM;
    }
    sAcc[w][c0 + 0] = a0; sAcc[w][c0 + 1] = a1;
    sAcc[w][c0 + 2] = a2; sAcc[w][c0 + 3] = a3;
    if (lane == 0) { sM[w] = M; sS[w] = S; }
    __syncthreads();
    if (w == 0) {
        float Mg = fmaxf(fmaxf(sM[0], sM[1]), fmaxf(sM[2], sM[3]));
        float e0 = __expf(sM[0] - Mg), e1 = __expf(sM[1] - Mg);
        float e2 = __expf(sM[2] - Mg), e3 = __expf(sM[3] - Mg);
        float St = sS[0] * e0 + sS[1] * e1 + sS[2] * e2 + sS[3] * e3;
        float inv = 1.0f / (St + 1e-12f);
        #pragma unroll
        for (int c = 0; c < 4; ++c) {
            float v = sAcc[0][c0 + c] * e0 + sAcc[1][c0 + c] * e1
                    + sAcc[2][c0 + c] * e2 + sAcc[3][c0 + c] * e3;
            pooled[(size_t)g * 256 + c0 + c] = f2b(v * inv);
        }
    }
}

// ---------------------------------------------------------------------------
extern "C" void kernel_launch(void* const* d_in, const int* in_sizes, int n_in,
                              void* d_out, int out_size, void* d_ws, size_t ws_size,
                              hipStream_t stream)
{
    const float* pos   = (const float*)d_in[0];
    const int*   z     = (const int*)d_in[1];
    const int*   batch = (const int*)d_in[2];
    const int*   ei    = (const int*)d_in[3];
    const float* emb   = (const float*)d_in[4];
    const float* W_in  = (const float*)d_in[5];
    const float* b_in  = (const float*)d_in[6];
    const float* Wq    = (const float*)d_in[7];
    const float* Wk    = (const float*)d_in[8];
    const float* Wv    = (const float*)d_in[9];
    const float* W_rbf = (const float*)d_in[10];
    const float* W_msg = (const float*)d_in[11];
    const float* W_vg  = (const float*)d_in[12];
    const float* W_vs  = (const float*)d_in[13];
    const float* W_nd  = (const float*)d_in[14];
    const float* b_nd  = (const float*)d_in[15];
    const float* gam   = (const float*)d_in[16];
    const float* watt  = (const float*)d_in[17];
    const float* W_out = (const float*)d_in[18];
    const float* b_out = (const float*)d_in[19];

    const int N = in_sizes[0] / 3;      // 20000
    const int E = in_sizes[3] / 2;      // 320000
    const int G = out_size / 512;       // 500

    char* ws = (char*)d_ws;
    size_t o = 0;
    auto alloc = [&](size_t bytes) -> char* {
        o = (o + 255) & ~(size_t)255;
        char* r = ws + o;
        o += bytes;
        return r;
    };
    u16*   h16     = (u16*)  alloc((size_t)N * 256 * 2);
    u16*   vf16    = (u16*)  alloc((size_t)N * 3 * 256 * 2);
    u16*   q16     = (u16*)  alloc((size_t)N * 128 * 2);
    u16*   kv8     = (u16*)  alloc((size_t)N * 128 * 2);
    u16*   umb     = (u16*)  alloc((size_t)N * 4 * 128 * 2);
    u16*   b2_16   = (u16*)  alloc((size_t)N * 256 * 2);
    u16*   pool16  = (u16*)  alloc((size_t)G * 256 * 2);
    u32*   f_table = (u32*)  alloc((size_t)4 * 4097 * 128 * 4);
    const size_t LS = 384 * 256 + 2 * (256 * 128) + 2 * (256 * 256);
    const size_t OFF_QKV = 0, OFF_VG = 384 * 256, OFF_MSG = OFF_VG + 256 * 128,
                 OFF_ND = OFF_MSG + 256 * 128, OFF_VS = OFF_ND + 256 * 256;
    const size_t OFF_OUT = LS * 4;
    u16* whi = (u16*)alloc((LS * 4 + 512 * 256) * sizeof(u16));
    u16* wlo = (u16*)alloc((LS * 4 + 512 * 256) * sizeof(u16));
    int*  i_deg   = (int*)alloc((size_t)N * 4);
    int*  i_rowp  = (int*)alloc((size_t)(N + 1) * 4);
    int*  i_cur   = (int*)alloc((size_t)(N + 1) * 4);
    int4* i_recs  = (int4*)alloc((size_t)E * 16);
    int*  i_gcnt  = (int*)alloc((size_t)G * 4);
    int*  i_gptr  = (int*)alloc((size_t)(G + 1) * 4);

    u16* U16   = umb;                         // [3N,128]
    u16* msg16 = umb + (size_t)3 * N * 128;   // [N,128]

    // ---- weight pre-pass descriptor ----
    TDesc td;
    int idx = 0;
    for (int l = 0; l < 4; ++l) {
        u16* bh = whi + (size_t)l * LS;
        u16* bl = wlo + (size_t)l * LS;
        td.e[idx++] = { Wq   + (size_t)l * 256 * 128, bh + OFF_QKV,             bl + OFF_QKV,             256, 128 };
        td.e[idx++] = { Wk   + (size_t)l * 256 * 128, bh + OFF_QKV + 128 * 256, bl + OFF_QKV + 128 * 256, 256, 128 };
        td.e[idx++] = { Wv   + (size_t)l * 256 * 128, bh + OFF_QKV + 256 * 256, bl + OFF_QKV + 256 * 256, 256, 128 };
        td.e[idx++] = { W_vg + (size_t)l * 128 * 256, bh + OFF_VG,  bl + OFF_VG,  128, 256 };
        td.e[idx++] = { W_msg+ (size_t)l * 128 * 256, bh + OFF_MSG, bl + OFF_MSG, 128, 256 };
        td.e[idx++] = { W_nd + (size_t)l * 256 * 256, bh + OFF_ND,  bl + OFF_ND,  256, 256 };
        td.e[idx++] = { W_vs + (size_t)l * 256 * 256, bh + OFF_VS,  bl + OFF_VS,  256, 256 };
    }
    td.e[idx++] = { W_out, whi + OFF_OUT, wlo + OFF_OUT, 256, 512 };

    // ---- setup ----
    zero2_i32<<<(N + G + 255) / 256, 256, 0, stream>>>(i_deg, N, i_gcnt, G);
    transpose_split<<<dim3(128, 29), 256, 0, stream>>>(td);
    build_rbf_table<<<dim3(4097, 4), 128, 0, stream>>>(W_rbf, f_table);

    setup_hist<<<(E + 255) / 256, 256, 0, stream>>>(ei, batch, E, N, i_deg, i_gcnt);
    scan2_kernel<<<2, 1024, 0, stream>>>(i_deg, N, i_rowp, i_cur, i_gcnt, G, i_gptr);
    scatter_kernel<<<(E + 255) / 256, 256, 0, stream>>>(ei, pos, i_cur, i_recs, E);
    init_h_kernel<<<N, 256, 0, stream>>>(z, pos, emb, W_in, b_in, h16);

    const int MB  = (N + 127) / 128;          // 157
    const int MB3 = (3 * N + 127) / 128;      // 469
    const int MBG = (G + 127) / 128;          // 4

    // ---- layers ----
    for (int l = 0; l < 4; ++l) {
        u16* bh = whi + (size_t)l * LS;
        u16* bl = wlo + (size_t)l * LS;
        const float* bnd_l = b_nd + (size_t)l * 256;
        const float* gam_l = gam  + (size_t)l * 256;
        const u32*   tbl_l = f_table + (size_t)l * 4097 * 128;

        // q16/kv8 = h @ [Wq|Wk|Wv]
        mfma_gemm<3,false,false,false,false><<<3 * MB, 256, 0, stream>>>(
            h16, bh + OFF_QKV, nullptr, nullptr, q16, kv8, N, 256, 384, 3);

        edge_attn_kernel<<<N, 128, 0, stream>>>(i_rowp, i_recs, q16, kv8,
                                                tbl_l, msg16, U16);

        // vfeat (+)= U @ W_vgate
        if (l == 0)
            mfma_gemm<1,false,false,false,false><<<2 * MB3, 256, 0, stream>>>(
                U16, bh + OFF_VG, nullptr, nullptr, vf16, nullptr, 3 * N, 128, 256, 2);
        else
            mfma_gemm<2,false,false,false,false><<<2 * MB3, 256, 0, stream>>>(
                U16, bh + OFF_VG, nullptr, nullptr, vf16, nullptr, 3 * N, 128, 256, 2);

        // b2 = gelu(gelu(msg@Wmsg) @ Wnd + bnd)   (fused MLP, b1 in LDS)
        mlp_kernel<<<MB, 512, 0, stream>>>(
            msg16, bh + OFF_MSG, bh + OFF_ND, bl + OFF_ND, bnd_l, b2_16, N);

        // h16 = LN(h16 + b2 + vnorm(vf)@Wvs) * gamma   (fused, inline vnorm)
        vs_ln_kernel<<<MB, 512, 0, stream>>>(
            vf16, bh + OFF_VS, bl + OFF_VS, b2_16, gam_l, h16, N);
    }

    // ---- readout ----
    pool_kernel<<<G, 256, 0, stream>>>(h16, watt, i_gptr, pool16);
    mfma_gemm<0,false,true,false,true><<<4 * MBG, 256, 0, stream>>>(
        pool16, whi + OFF_OUT, wlo + OFF_OUT, b_out, (float*)d_out, nullptr, G, 256, 512, 4);
}

// Round 14
// 804.012 us; speedup vs baseline: 1.0492x; 1.0492x over previous
//
#include <hip/hip_runtime.h>
#include <math.h>

typedef unsigned char  u8;
typedef unsigned short u16;
typedef unsigned int   u32;
typedef __attribute__((ext_vector_type(8))) unsigned short ushort8;
typedef __attribute__((ext_vector_type(4))) unsigned short ushort4v;
typedef __attribute__((ext_vector_type(8))) short short8v;   // 8 bf16 (4 VGPRs)
typedef __attribute__((ext_vector_type(4))) float f32x4;
typedef __attribute__((ext_vector_type(2))) float f32x2;

__device__ __forceinline__ float gelu_f(float x) {
    const float c = 0.7978845608028654f;   // sqrt(2/pi)
    float x3 = x * x * x;
    float t = tanhf(c * (x + 0.044715f * x3));
    return 0.5f * x * (1.0f + t);
}

__device__ __forceinline__ u16 f2b(float f) {
    u32 u = __float_as_uint(f);
    return (u16)((u + 0x7FFFu + ((u >> 16) & 1u)) >> 16);
}
__device__ __forceinline__ float b2f(u16 u) {
    return __uint_as_float(((u32)u) << 16);
}

// fp8 e4m3fn software fallback
__device__ __forceinline__ u32 f2fp8_sw(float f) {
    u32 u = __float_as_uint(f);
    u32 s = (u >> 31) << 7;
    float af = fabsf(f);
    if (af >= 448.0f) return s | 0x7E;
    if (af < 0.015625f) {
        int m = __float2int_rn(af * 512.0f);
        if (m >= 8) return s | 0x08;
        return s | (u32)m;
    }
    u32 a = __float_as_uint(af);
    u32 r = a + 0xFFFFFu + ((a >> 20) & 1u);
    int e8 = (int)(r >> 23) - 120;
    u32 m3 = (r >> 20) & 7u;
    if (e8 >= 16) return s | 0x7E;
    return s | ((u32)e8 << 3) | m3;
}
__device__ __forceinline__ float fp8d_sw(u32 b) {
    u32 lo = b & 0x7Fu;
    u32 nb = (lo << 20) + 0x3C000000u;
    float n = __uint_as_float(nb | ((b & 0x80u) << 24));
    float sub = (float)(b & 7u) * 0.001953125f;
    sub = (b & 0x80u) ? -sub : sub;
    return (lo & 0x78u) ? n : sub;
}
__device__ __forceinline__ u8 f2fp8(float v) {
#if __has_builtin(__builtin_amdgcn_cvt_pk_fp8_f32)
    return (u8)(__builtin_amdgcn_cvt_pk_fp8_f32(v, v, 0, false) & 0xFF);
#else
    return (u8)f2fp8_sw(v);
#endif
}
__device__ __forceinline__ f32x2 kvdec(u32 pair) {
#if __has_builtin(__builtin_amdgcn_cvt_pk_f32_fp8)
    return __builtin_amdgcn_cvt_pk_f32_fp8((int)pair, false);
#else
    f32x2 r;
    r[0] = fp8d_sw(pair & 0xFF);
    r[1] = fp8d_sw((pair >> 8) & 0xFF);
    return r;
#endif
}

__device__ __forceinline__ void split_bf16(float f, u16& h, u16& l) {
    u32 u = __float_as_uint(f);
    u32 r = (u + 0x7FFFu + ((u >> 16) & 1u)) >> 16;
    h = (u16)r;
    float hf = __uint_as_float(r << 16);
    float d = f - hf;
    u32 u2 = __float_as_uint(d);
    l = (u16)((u2 + 0x7FFFu + ((u2 >> 16) & 1u)) >> 16);
}

// bijective XCD-chunked swizzle (m204)
__device__ __forceinline__ int xcd_swz(int orig, int nwg) {
    int q8 = nwg >> 3, r8 = nwg & 7;
    int xcd = orig & 7, ii = orig >> 3;
    return (xcd < r8 ? xcd * (q8 + 1) : r8 * (q8 + 1) + (xcd - r8) * q8) + ii;
}

// ---------------------------------------------------------------------------
__global__ __launch_bounds__(256) void zero2_i32(int* __restrict__ a, int na,
                                                 int* __restrict__ b, int nb) {
    int i = blockIdx.x * 256 + threadIdx.x;
    if (i < na) a[i] = 0;
    else if (i - na < nb) b[i - na] = 0;
}

// ---------------------------------------------------------------------------
// Weight pre-pass: transpose [K][N] f32 -> [N][K] split bf16 hi/lo
// ---------------------------------------------------------------------------
struct TEntry { const float* src; u16* dh; u16* dl; int K; int N; };
struct TDesc  { TEntry e[29]; };

__global__ __launch_bounds__(256) void transpose_split(TDesc desc) {
    __shared__ float tile[32][33];
    TEntry en = desc.e[blockIdx.y];
    int tk = en.K >> 5, tn = en.N >> 5;
    int bx = blockIdx.x;
    if (bx >= tk * tn) return;
    int k0 = (bx % tk) * 32, n0 = (bx / tk) * 32;
    int tx = threadIdx.x & 31, ty = threadIdx.x >> 5;
    #pragma unroll
    for (int yy = 0; yy < 32; yy += 8)
        tile[ty + yy][tx] = en.src[(size_t)(k0 + ty + yy) * en.N + (n0 + tx)];
    __syncthreads();
    #pragma unroll
    for (int yy = 0; yy < 32; yy += 8) {
        int n = n0 + ty + yy, k = k0 + tx;
        float f = tile[tx][ty + yy];
        u16 h, l;
        split_bf16(f, h, l);
        en.dh[(size_t)n * en.K + k] = h;
        en.dl[(size_t)n * en.K + k] = l;
    }
}

// ---------------------------------------------------------------------------
// RBF lookup tables: packed bf16 pairs (val[k], val[k+1]) per u32, 4097/layer
// ---------------------------------------------------------------------------
__device__ __forceinline__ float rbf_val(int k, const float* __restrict__ Wrbf_l, int m) {
    const float PI = 3.14159265358979323846f;
    float d = fmaxf((float)k * (6.0f / 4096.0f), 1e-9f);
    float th = d * (PI / 6.0f);
    float s1, c1;
    __sincosf(th, &s1, &c1);
    float env = (d < 6.0f) ? (0.5f * c1 + 0.5f) : 0.0f;
    float invd = 1.0f / d;
    float two_c = 2.0f * c1;
    float sp = 0.f, sc = s1, dot = 0.f;
    #pragma unroll
    for (int r = 0; r < 32; ++r) {
        dot = fmaf(sc, Wrbf_l[r * 128 + m], dot);
        float sn = fmaf(two_c, sc, -sp);
        sp = sc; sc = sn;
    }
    return dot * invd * env;
}

__global__ __launch_bounds__(128) void build_rbf_table(
    const float* __restrict__ W_rbf, u32* __restrict__ table)
{
    int k = blockIdx.x, l = blockIdx.y, m = threadIdx.x;
    const float* Wrbf_l = W_rbf + (size_t)l * 32 * 128;
    float v0 = rbf_val(k, Wrbf_l, m);
    float v1 = rbf_val(k + 1, Wrbf_l, m);
    table[((size_t)l * 4097 + k) * 128 + m] = (u32)f2b(v0) | ((u32)f2b(v1) << 16);
}

// ---------------------------------------------------------------------------
// MFMA GEMM, 1D swizzled grid. A bf16 [M][K]; BH (+BL) transposed bf16 [N][K].
// OMODE: 0 f32 out (ACCUM f32 +=), 1 bf16 out, 2 bf16 out + bf16 accum,
//        3 qkv mixed (Q bf16 / K,V fp8 pairs)
// ---------------------------------------------------------------------------
template<int OMODE, bool ACCUM, bool BIAS, bool DOGELU, bool SPLITB>
__global__ __launch_bounds__(256) void mfma_gemm(
    const u16* __restrict__ A, const u16* __restrict__ BH,
    const u16* __restrict__ BL, const float* __restrict__ bias,
    void* __restrict__ Cv, void* __restrict__ Cv2,
    int Mrows, int K, int Nc, int gx)
{
    constexpr bool STAGE_OUT = (OMODE == 1 || OMODE == 2);
    constexpr int MAIN_B = 128 * 40 * 2 * (SPLITB ? 3 : 2);
    constexpr int OUT_B  = STAGE_OUT ? 128 * 136 * 2 : 0;
    constexpr int SMEM_B = (MAIN_B > OUT_B) ? MAIN_B : OUT_B;
    __shared__ __align__(16) char smem[SMEM_B];
    u16 (*sA)[40]  = (u16(*)[40])smem;
    u16 (*sBh)[40] = (u16(*)[40])(smem + 128 * 40 * 2);
    u16 (*sBl)[40] = (u16(*)[40])(smem + 2 * 128 * 40 * 2);
    u16 (*sOut)[136] = (u16(*)[136])smem;

    const int wg = xcd_swz(blockIdx.x, gridDim.x);
    const int r0 = (wg / gx) * 128, c0 = (wg % gx) * 128;

    const int t = threadIdx.x;
    const int lane = t & 63, wid = t >> 6;
    const int wr = (wid >> 1) * 64, wc = (wid & 1) * 64;

    f32x4 acc[4][4] = {};

    const int srow = t >> 1;
    const int skc  = (t & 1) * 16;

    for (int k0 = 0; k0 < K; k0 += 32) {
        {
            int gr = r0 + srow;
            ushort8 h0, h1;
            if (gr < Mrows) {
                const u16* p = A + (size_t)gr * K + (k0 + skc);
                h0 = *(const ushort8*)p;
                h1 = *(const ushort8*)(p + 8);
            } else {
                #pragma unroll
                for (int j = 0; j < 8; ++j) { h0[j] = 0; h1[j] = 0; }
            }
            *(ushort8*)&sA[srow][skc]     = h0;
            *(ushort8*)&sA[srow][skc + 8] = h1;
        }
        {
            int cg = c0 + srow;
            const u16* ph = BH + (size_t)cg * K + (k0 + skc);
            *(ushort8*)&sBh[srow][skc]     = *(const ushort8*)(ph);
            *(ushort8*)&sBh[srow][skc + 8] = *(const ushort8*)(ph + 8);
            if constexpr (SPLITB) {
                const u16* pl = BL + (size_t)cg * K + (k0 + skc);
                *(ushort8*)&sBl[srow][skc]     = *(const ushort8*)(pl);
                *(ushort8*)&sBl[srow][skc + 8] = *(const ushort8*)(pl + 8);
            }
        }
        __syncthreads();

        const int arow = wr + (lane & 15);
        const int koff = (lane >> 4) * 8;
        short8v ah[4];
        #pragma unroll
        for (int fr = 0; fr < 4; ++fr)
            ah[fr] = *(const short8v*)&sA[arow + fr * 16][koff];
        #pragma unroll
        for (int fc = 0; fc < 4; ++fc) {
            int bcol = wc + fc * 16 + (lane & 15);
            short8v bh = *(const short8v*)&sBh[bcol][koff];
            #pragma unroll
            for (int fr = 0; fr < 4; ++fr)
                acc[fr][fc] = __builtin_amdgcn_mfma_f32_16x16x32_bf16(ah[fr], bh, acc[fr][fc], 0, 0, 0);
            if constexpr (SPLITB) {
                short8v bl = *(const short8v*)&sBl[bcol][koff];
                #pragma unroll
                for (int fr = 0; fr < 4; ++fr)
                    acc[fr][fc] = __builtin_amdgcn_mfma_f32_16x16x32_bf16(ah[fr], bl, acc[fr][fc], 0, 0, 0);
            }
        }
        __syncthreads();
    }

    if constexpr (STAGE_OUT) {
        #pragma unroll
        for (int fr = 0; fr < 4; ++fr) {
            int rbase = wr + fr * 16 + (lane >> 4) * 4;
            #pragma unroll
            for (int fc = 0; fc < 4; ++fc) {
                int col = wc + fc * 16 + (lane & 15);
                #pragma unroll
                for (int reg = 0; reg < 4; ++reg) {
                    float v = acc[fr][fc][reg];
                    if (BIAS)   v += bias[c0 + col];
                    if (DOGELU) v = gelu_f(v);
                    sOut[rbase + reg][col] = f2b(v);
                }
            }
        }
        __syncthreads();
        #pragma unroll
        for (int p = 0; p < 4; ++p) {
            int row = p * 32 + (t >> 3);
            int cch = (t & 7) * 16;
            int gr = r0 + row;
            if (gr < Mrows) {
                u16* gp = (u16*)Cv + (size_t)gr * Nc + c0 + cch;
                ushort8 v0 = *(ushort8*)&sOut[row][cch];
                ushort8 v1 = *(ushort8*)&sOut[row][cch + 8];
                if (OMODE == 2) {
                    ushort8 o0 = *(const ushort8*)gp;
                    ushort8 o1 = *(const ushort8*)(gp + 8);
                    #pragma unroll
                    for (int j = 0; j < 8; ++j) {
                        v0[j] = f2b(b2f(v0[j]) + b2f(o0[j]));
                        v1[j] = f2b(b2f(v1[j]) + b2f(o1[j]));
                    }
                }
                *(ushort8*)gp       = v0;
                *(ushort8*)(gp + 8) = v1;
            }
        }
    } else {
        #pragma unroll
        for (int fr = 0; fr < 4; ++fr) {
            int rbase = r0 + wr + fr * 16 + (lane >> 4) * 4;
            #pragma unroll
            for (int fc = 0; fc < 4; ++fc) {
                int col = c0 + wc + fc * 16 + (lane & 15);
                #pragma unroll
                for (int reg = 0; reg < 4; ++reg) {
                    int gr = rbase + reg;
                    if (gr >= Mrows) continue;
                    float v = acc[fr][fc][reg];
                    if (BIAS)   v += bias[col];
                    if (DOGELU) v = gelu_f(v);
                    if (OMODE == 0) {
                        float* pc = (float*)Cv + (size_t)gr * Nc + col;
                        if (ACCUM) v += *pc;
                        *pc = v;
                    } else {   // OMODE 3: qkv mixed
                        if (col < 128)
                            ((u16*)Cv)[(size_t)gr * 128 + col] = f2b(v);
                        else if (col < 256)
                            ((u8*)Cv2)[(size_t)gr * 256 + (col - 128) * 2] = f2fp8(v);
                        else
                            ((u8*)Cv2)[(size_t)gr * 256 + (col - 256) * 2 + 1] = f2fp8(v);
                    }
                }
            }
        }
    }
}

// ---------------------------------------------------------------------------
// Fused MLP: b2 = gelu(gelu(msg@Wmsg) @ Wnd + bnd).  BM=128, BN=256, 8 waves.
// ---------------------------------------------------------------------------
__global__ __launch_bounds__(512) void mlp_kernel(
    const u16* __restrict__ msg, const u16* __restrict__ Wmsg,
    const u16* __restrict__ WndH, const u16* __restrict__ WndL,
    const float* __restrict__ bnd, u16* __restrict__ b2out, int Mrows)
{
    __shared__ __align__(16) u16 b1[128][264];
    __shared__ __align__(16) char sbuf[256 * 40 * 2 * 2];
    u16 (*sA)[40]   = (u16(*)[40])sbuf;
    u16 (*sB)[40]   = (u16(*)[40])(sbuf + 128 * 40 * 2);
    u16 (*sBh)[40]  = (u16(*)[40])sbuf;
    u16 (*sBl)[40]  = (u16(*)[40])(sbuf + 256 * 40 * 2);
    u16 (*sOut)[136] = (u16(*)[136])sbuf;

    const int r0 = xcd_swz(blockIdx.x, gridDim.x) * 128;
    const int t = threadIdx.x;
    const int lane = t & 63, wid = t >> 6;
    const int wr = (wid >> 2) * 64, wc = (wid & 3) * 64;

    f32x4 acc[4][4] = {};
    const int srowA = t >> 2, skcA = (t & 3) * 8;
    const int srowB = t >> 1, skcB = (t & 1) * 16;

    for (int k0 = 0; k0 < 128; k0 += 32) {
        {
            int gr = r0 + srowA;
            ushort8 h0;
            #pragma unroll
            for (int j = 0; j < 8; ++j) h0[j] = 0;
            if (gr < Mrows) h0 = *(const ushort8*)(msg + (size_t)gr * 128 + k0 + skcA);
            *(ushort8*)&sA[srowA][skcA] = h0;
        }
        {
            const u16* p = Wmsg + (size_t)srowB * 128 + k0 + skcB;
            *(ushort8*)&sB[srowB][skcB]     = *(const ushort8*)p;
            *(ushort8*)&sB[srowB][skcB + 8] = *(const ushort8*)(p + 8);
        }
        __syncthreads();
        const int arow = wr + (lane & 15);
        const int koff = (lane >> 4) * 8;
        short8v ah[4];
        #pragma unroll
        for (int fr = 0; fr < 4; ++fr)
            ah[fr] = *(const short8v*)&sA[arow + fr * 16][koff];
        #pragma unroll
        for (int fc = 0; fc < 4; ++fc) {
            int bcol = wc + fc * 16 + (lane & 15);
            short8v bh = *(const short8v*)&sB[bcol][koff];
            #pragma unroll
            for (int fr = 0; fr < 4; ++fr)
                acc[fr][fc] = __builtin_amdgcn_mfma_f32_16x16x32_bf16(ah[fr], bh, acc[fr][fc], 0, 0, 0);
        }
        __syncthreads();
    }
    #pragma unroll
    for (int fr = 0; fr < 4; ++fr) {
        int rbase = wr + fr * 16 + (lane >> 4) * 4;
        #pragma unroll
        for (int fc = 0; fc < 4; ++fc) {
            int col = wc + fc * 16 + (lane & 15);
            #pragma unroll
            for (int reg = 0; reg < 4; ++reg) {
                b1[rbase + reg][col] = f2b(gelu_f(acc[fr][fc][reg]));
                acc[fr][fc][reg] = 0.0f;
            }
        }
    }
    __syncthreads();

    for (int k0 = 0; k0 < 256; k0 += 32) {
        {
            const u16* ph = WndH + (size_t)srowB * 256 + k0 + skcB;
            const u16* pl = WndL + (size_t)srowB * 256 + k0 + skcB;
            *(ushort8*)&sBh[srowB][skcB]     = *(const ushort8*)ph;
            *(ushort8*)&sBh[srowB][skcB + 8] = *(const ushort8*)(ph + 8);
            *(ushort8*)&sBl[srowB][skcB]     = *(const ushort8*)pl;
            *(ushort8*)&sBl[srowB][skcB + 8] = *(const ushort8*)(pl + 8);
        }
        __syncthreads();
        const int arow = wr + (lane & 15);
        const int koff = (lane >> 4) * 8;
        short8v ah[4];
        #pragma unroll
        for (int fr = 0; fr < 4; ++fr)
            ah[fr] = *(const short8v*)&b1[arow + fr * 16][k0 + koff];
        #pragma unroll
        for (int fc = 0; fc < 4; ++fc) {
            int bcol = wc + fc * 16 + (lane & 15);
            short8v bh = *(const short8v*)&sBh[bcol][koff];
            short8v bl = *(const short8v*)&sBl[bcol][koff];
            #pragma unroll
            for (int fr = 0; fr < 4; ++fr) {
                acc[fr][fc] = __builtin_amdgcn_mfma_f32_16x16x32_bf16(ah[fr], bh, acc[fr][fc], 0, 0, 0);
                acc[fr][fc] = __builtin_amdgcn_mfma_f32_16x16x32_bf16(ah[fr], bl, acc[fr][fc], 0, 0, 0);
            }
        }
        __syncthreads();
    }

    #pragma unroll
    for (int fr = 0; fr < 4; ++fr) {
        int rbase = wr + fr * 16 + (lane >> 4) * 4;
        #pragma unroll
        for (int fc = 0; fc < 4; ++fc) {
            int col = wc + fc * 16 + (lane & 15);
            #pragma unroll
            for (int reg = 0; reg < 4; ++reg)
                sOut[rbase + reg][col] = f2b(gelu_f(acc[fr][fc][reg] + bnd[col]));
        }
    }
    __syncthreads();
    #pragma unroll
    for (int p = 0; p < 2; ++p) {
        int row = p * 64 + (t >> 3);
        int cch = (t & 7) * 16;
        int gr = r0 + row;
        if (gr < Mrows) {
            u16* gp = b2out + (size_t)gr * 256 + cch;
            *(ushort8*)gp       = *(ushort8*)&sOut[row][cch];
            *(ushort8*)(gp + 8) = *(ushort8*)&sOut[row][cch + 8];
        }
    }
}

// ---------------------------------------------------------------------------
// Fused vs-GEMM + LayerNorm, vnorm inline.
// ---------------------------------------------------------------------------
__global__ __launch_bounds__(512) void vs_ln_kernel(
    const u16* __restrict__ vf, const u16* __restrict__ BH,
    const u16* __restrict__ BL, const u16* __restrict__ b2,
    const float* __restrict__ gamma_l, u16* __restrict__ h16, int Mrows)
{
    __shared__ __align__(16) u16 sA [128][40];
    __shared__ __align__(16) u16 sBh[256][40];
    __shared__ __align__(16) u16 sBl[256][40];
    __shared__ float sSum[128][4];
    __shared__ float sSq [128][4];

    const int r0 = blockIdx.x * 128;
    const int t = threadIdx.x;
    const int lane = t & 63, wid = t >> 6;
    const int wr = (wid >> 2) * 64, wc = (wid & 3) * 64;

    f32x4 acc[4][4] = {};
    const int K = 256;
    const int srow = t >> 2;
    const int skc  = (t & 3) * 8;

    for (int k0 = 0; k0 < K; k0 += 32) {
        {
            int gr = r0 + srow;
            ushort8 h0;
            #pragma unroll
            for (int j = 0; j < 8; ++j) h0[j] = 0;
            if (gr < Mrows) {
                const u16* base = vf + ((size_t)gr * 3) * 256 + k0 + skc;
                ushort8 v0 = *(const ushort8*)(base);
                ushort8 v1 = *(const ushort8*)(base + 256);
                ushort8 v2 = *(const ushort8*)(base + 512);
                #pragma unroll
                for (int j = 0; j < 8; ++j) {
                    float a = b2f(v0[j]), b = b2f(v1[j]), c = b2f(v2[j]);
                    h0[j] = f2b(sqrtf(a * a + b * b + c * c + 1e-8f));
                }
            }
            *(ushort8*)&sA[srow][skc] = h0;
        }
        {
            *(ushort8*)&sBh[srow][skc]       = *(const ushort8*)(BH + (size_t)srow * K + k0 + skc);
            *(ushort8*)&sBh[srow + 128][skc] = *(const ushort8*)(BH + (size_t)(srow + 128) * K + k0 + skc);
            *(ushort8*)&sBl[srow][skc]       = *(const ushort8*)(BL + (size_t)srow * K + k0 + skc);
            *(ushort8*)&sBl[srow + 128][skc] = *(const ushort8*)(BL + (size_t)(srow + 128) * K + k0 + skc);
        }
        __syncthreads();

        const int arow = wr + (lane & 15);
        const int koff = (lane >> 4) * 8;
        short8v ah[4];
        #pragma unroll
        for (int fr = 0; fr < 4; ++fr)
            ah[fr] = *(const short8v*)&sA[arow + fr * 16][koff];
        #pragma unroll
        for (int fc = 0; fc < 4; ++fc) {
            int bcol = wc + fc * 16 + (lane & 15);
            short8v bh = *(const short8v*)&sBh[bcol][koff];
            short8v bl = *(const short8v*)&sBl[bcol][koff];
            #pragma unroll
            for (int fr = 0; fr < 4; ++fr) {
                acc[fr][fc] = __builtin_amdgcn_mfma_f32_16x16x32_bf16(ah[fr], bh, acc[fr][fc], 0, 0, 0);
                acc[fr][fc] = __builtin_amdgcn_mfma_f32_16x16x32_bf16(ah[fr], bl, acc[fr][fc], 0, 0, 0);
            }
        }
        __syncthreads();
    }

    float psum[4][4] = {}, psq[4][4] = {};
    #pragma unroll
    for (int fr = 0; fr < 4; ++fr) {
        #pragma unroll
        for (int fc = 0; fc < 4; ++fc) {
            int col = wc + fc * 16 + (lane & 15);
            #pragma unroll
            for (int reg = 0; reg < 4; ++reg) {
                int gr = r0 + wr + fr * 16 + (lane >> 4) * 4 + reg;
                float x = 0.f;
                if (gr < Mrows) {
                    size_t ix = (size_t)gr * 256 + col;
                    x = acc[fr][fc][reg] + b2f(b2[ix]) + b2f(h16[ix]);
                }
                acc[fr][fc][reg] = x;
                psum[fr][reg] += x;
                psq[fr][reg]  = fmaf(x, x, psq[fr][reg]);
            }
        }
    }
    #pragma unroll
    for (int fr = 0; fr < 4; ++fr) {
        #pragma unroll
        for (int reg = 0; reg < 4; ++reg) {
            float s = psum[fr][reg], sq = psq[fr][reg];
            #pragma unroll
            for (int off = 8; off; off >>= 1) {
                s  += __shfl_xor(s, off);
                sq += __shfl_xor(sq, off);
            }
            psum[fr][reg] = s; psq[fr][reg] = sq;
        }
    }
    if ((lane & 15) == 0) {
        int qg = lane >> 4;
        #pragma unroll
        for (int fr = 0; fr < 4; ++fr) {
            #pragma unroll
            for (int reg = 0; reg < 4; ++reg) {
                int row = wr + fr * 16 + qg * 4 + reg;
                sSum[row][wc >> 6] = psum[fr][reg];
                sSq [row][wc >> 6] = psq[fr][reg];
            }
        }
    }
    __syncthreads();
    #pragma unroll
    for (int fr = 0; fr < 4; ++fr) {
        #pragma unroll
        for (int reg = 0; reg < 4; ++reg) {
            int row = wr + fr * 16 + (lane >> 4) * 4 + reg;
            int gr = r0 + row;
            if (gr >= Mrows) continue;
            float S = sSum[row][0] + sSum[row][1] + sSum[row][2] + sSum[row][3];
            float Q = sSq[row][0] + sSq[row][1] + sSq[row][2] + sSq[row][3];
            float mu = S * (1.0f / 256.0f);
            float var = fmaxf(Q * (1.0f / 256.0f) - mu * mu, 0.0f);
            float rs = rsqrtf(var + 1e-5f);
            #pragma unroll
            for (int fc = 0; fc < 4; ++fc) {
                int col = wc + fc * 16 + (lane & 15);
                float y = (acc[fr][fc][reg] - mu) * rs * gamma_l[col];
                h16[(size_t)gr * 256 + col] = f2b(y);
            }
        }
    }
}

// ---------------------------------------------------------------------------
// Setup: per-edge degree hist + geometry, per-node graph hist (one kernel)
// ---------------------------------------------------------------------------
__global__ __launch_bounds__(256) void setup_edges(
    const int* __restrict__ ei, const int* __restrict__ batch,
    const float* __restrict__ pos, int E_, int Nn,
    int* __restrict__ deg, int* __restrict__ gcnt, float4* __restrict__ eg)
{
    int x = blockIdx.x * 256 + threadIdx.x;
    if (x < E_) {
        int s = ei[x], dn = ei[E_ + x];
        atomicAdd(&deg[dn], 1);
        float dx = pos[s * 3 + 0] - pos[dn * 3 + 0];
        float dy = pos[s * 3 + 1] - pos[dn * 3 + 1];
        float dz = pos[s * 3 + 2] - pos[dn * 3 + 2];
        float d = sqrtf(dx * dx + dy * dy + dz * dz + 1e-12f);
        float invd = 1.0f / d;
        eg[x] = make_float4(dx * invd, dy * invd, dz * invd, d);
    }
    if (x < Nn) atomicAdd(&gcnt[batch[x]], 1);
}

// two scans in one launch
__global__ __launch_bounds__(1024) void scan2_kernel(
    const int* __restrict__ cntA, int nA, int* __restrict__ outA, int* __restrict__ curA,
    const int* __restrict__ cntB, int nB, int* __restrict__ outB)
{
    __shared__ int part[1024];
    const int* cnt = (blockIdx.x == 0) ? cntA : cntB;
    int n          = (blockIdx.x == 0) ? nA : nB;
    int* out       = (blockIdx.x == 0) ? outA : outB;
    int* cursor    = (blockIdx.x == 0) ? curA : (int*)nullptr;
    int t = threadIdx.x;
    int chunk = (n + 1023) / 1024;
    int base = t * chunk;
    int s = 0;
    for (int k = 0; k < chunk; ++k) { int i = base + k; if (i < n) s += cnt[i]; }
    part[t] = s;
    __syncthreads();
    for (int off = 1; off < 1024; off <<= 1) {
        int u = (t >= off) ? part[t - off] : 0;
        __syncthreads();
        part[t] += u;
        __syncthreads();
    }
    int run = part[t] - s;
    for (int k = 0; k < chunk; ++k) {
        int i = base + k;
        if (i < n) {
            out[i] = run;
            if (cursor) cursor[i] = run;
            run += cnt[i];
        }
    }
    if (t == 1023) out[n] = part[1023];
}

// perm payload: (edge id, src node)
__global__ void scatter_kernel(const int* __restrict__ ei, int* __restrict__ cursor,
                               int2* __restrict__ perm2, int E_) {
    int e = blockIdx.x * 256 + threadIdx.x;
    if (e < E_) {
        int p = atomicAdd(&cursor[ei[E_ + e]], 1);
        perm2[p] = make_int2(e, ei[e]);
    }
}

// ---------------------------------------------------------------------------
// h init -> bf16
// ---------------------------------------------------------------------------
__global__ __launch_bounds__(256) void init_h_kernel(
    const int* __restrict__ z, const float* __restrict__ pos,
    const float* __restrict__ emb, const float* __restrict__ W_in,
    const float* __restrict__ b_in, u16* __restrict__ h16)
{
    int i = blockIdx.x, d = threadIdx.x;
    float acc = b_in[d];
    int zi = z[i];
    #pragma unroll 8
    for (int k = 0; k < 32; ++k)
        acc += emb[zi * 32 + k] * W_in[k * 256 + d];
    #pragma unroll
    for (int x = 0; x < 3; ++x)
        acc += pos[i * 3 + x] * W_in[(32 + x) * 256 + d];
    h16[(size_t)i * 256 + d] = f2b(acc);
}

// ---------------------------------------------------------------------------
// Per-dst-node edge attention, online softmax, 8 edges/iter.
// q16 bf16 [N][128]; kv8 fp8 pairs [N][128]; perm2 = (e, src);
// ew via packed bf16 table pair (single u32 load per edge).
// ---------------------------------------------------------------------------
__global__ __launch_bounds__(128) void edge_attn_kernel(
    const int* __restrict__ rowptr, const int2* __restrict__ perm2,
    const u16* __restrict__ q16, const u16* __restrict__ kv8,
    const float4* __restrict__ eg, const u32* __restrict__ table_l,
    u16* __restrict__ msg, u16* __restrict__ U)
{
    int m = threadIdx.x;
    int i = blockIdx.x;

    int p0 = rowptr[i], p1 = rowptr[i + 1];
    float q = b2f(q16[(size_t)i * 128 + m]);
    float Mx = -1e30f, S = 0.f, am = 0.f, a0 = 0.f, a1 = 0.f, a2 = 0.f;
    const float iscale = 0.1767766952966369f;   // 1/sqrt(32)

    for (int p = p0; p < p1; p += 8) {
        int rem = p1 - p;
        int ee[8], jj[8];
        #pragma unroll
        for (int u = 0; u < 8; ++u) {
            int pp = p + (u < rem ? u : 0);
            int2 pe = perm2[pp];
            ee[u] = __builtin_amdgcn_readfirstlane(pe.x);
            jj[u] = __builtin_amdgcn_readfirstlane(pe.y);
        }
        u32 kv[8];
        float4 g[8];
        #pragma unroll
        for (int u = 0; u < 8; ++u) {
            kv[u] = kv8[(size_t)jj[u] * 128 + m];
            g[u]  = eg[ee[u]];
        }
        float lg[8], vd[8];
        #pragma unroll
        for (int u = 0; u < 8; ++u) {
            f32x2 c = kvdec(kv[u]);
            vd[u] = c[1];
            float pr = q * c[0];
            #pragma unroll
            for (int off = 16; off; off >>= 1) pr += __shfl_xor(pr, off);
            lg[u] = pr * iscale;
        }
        float ew[8];
        #pragma unroll
        for (int u = 0; u < 8; ++u) {
            float x = fminf(g[u].w * (4096.0f / 6.0f), 4096.0f);
            int b = (int)x;
            float tf = x - (float)b;
            u32 pr = table_l[(size_t)b * 128 + m];
            float f0 = b2f((u16)(pr & 0xFFFF));
            float f1 = b2f((u16)(pr >> 16));
            ew[u] = fmaf(tf, f1 - f0, f0);
        }
        float Mb = Mx;
        #pragma unroll
        for (int u = 0; u < 8; ++u) Mb = fmaxf(Mb, lg[u]);
        float sc = __expf(Mx - Mb);
        float ws = 0.f, wvs = 0.f, wx = 0.f, wy = 0.f, wz = 0.f;
        #pragma unroll
        for (int u = 0; u < 8; ++u) {
            float w = (u < rem) ? __expf(lg[u] - Mb) : 0.f;
            float wv = w * vd[u] * ew[u];
            ws  += w;
            wvs += wv;
            wx = fmaf(wv, g[u].x, wx);
            wy = fmaf(wv, g[u].y, wy);
            wz = fmaf(wv, g[u].z, wz);
        }
        S  = S  * sc + ws;
        am = am * sc + wvs;
        a0 = a0 * sc + wx;
        a1 = a1 * sc + wy;
        a2 = a2 * sc + wz;
        Mx = Mb;
    }
    float inv = 1.0f / (S + 1e-12f);
    msg[(size_t)i * 128 + m] = f2b(am * inv);
    U[((size_t)i * 3 + 0) * 128 + m] = f2b(a0 * inv);
    U[((size_t)i * 3 + 1) * 128 + m] = f2b(a1 * inv);
    U[((size_t)i * 3 + 2) * 128 + m] = f2b(a2 * inv);
}

// ---------------------------------------------------------------------------
// Graph pooling, wave-parallel (block = graph)
// ---------------------------------------------------------------------------
__global__ __launch_bounds__(256) void pool_kernel(
    const u16* __restrict__ h16, const float* __restrict__ w_att,
    const int* __restrict__ gptr, u16* __restrict__ pooled)
{
    __shared__ float sM[4], sS[4];
    __shared__ float sAcc[4][256];
    int g = blockIdx.x;
    int t = threadIdx.x, w = t >> 6, lane = t & 63;
    int c0 = lane * 4;
    int n0 = gptr[g], n1 = gptr[g + 1];
    float4 wa = *(const float4*)(w_att + c0);
    float M = -1e30f, S = 0.f, a0 = 0.f, a1 = 0.f, a2 = 0.f, a3 = 0.f;
    for (int i = n0 + w; i < n1; i += 4) {
        ushort4v hv = *(const ushort4v*)(h16 + (size_t)i * 256 + c0);
        float h0 = b2f(hv[0]), h1 = b2f(hv[1]), h2 = b2f(hv[2]), h3 = b2f(hv[3]);
        float p = h0 * wa.x + h1 * wa.y + h2 * wa.z + h3 * wa.w;
        #pragma unroll
        for (int off = 32; off; off >>= 1) p += __shfl_xor(p, off);
        float nM = fmaxf(M, p);
        float sc = __expf(M - nM), wg = __expf(p - nM);
        S = S * sc + wg;
        a0 = a0 * sc + wg * h0;
        a1 = a1 * sc + wg * h1;
        a2 = a2 * sc + wg * h2;
        a3 = a3 * sc + wg * h3;
        M = nM;
    }
    sAcc[w][c0 + 0] = a0; sAcc[w][c0 + 1] = a1;
    sAcc[w][c0 + 2] = a2; sAcc[w][c0 + 3] = a3;
    if (lane == 0) { sM[w] = M; sS[w] = S; }
    __syncthreads();
    if (w == 0) {
        float Mg = fmaxf(fmaxf(sM[0], sM[1]), fmaxf(sM[2], sM[3]));
        float e0 = __expf(sM[0] - Mg), e1 = __expf(sM[1] - Mg);
        float e2 = __expf(sM[2] - Mg), e3 = __expf(sM[3] - Mg);
        float St = sS[0] * e0 + sS[1] * e1 + sS[2] * e2 + sS[3] * e3;
        float inv = 1.0f / (St + 1e-12f);
        #pragma unroll
        for (int c = 0; c < 4; ++c) {
            float v = sAcc[0][c0 + c] * e0 + sAcc[1][c0 + c] * e1
                    + sAcc[2][c0 + c] * e2 + sAcc[3][c0 + c] * e3;
            pooled[(size_t)g * 256 + c0 + c] = f2b(v * inv);
        }
    }
}

// ---------------------------------------------------------------------------
extern "C" void kernel_launch(void* const* d_in, const int* in_sizes, int n_in,
                              void* d_out, int out_size, void* d_ws, size_t ws_size,
                              hipStream_t stream)
{
    const float* pos   = (const float*)d_in[0];
    const int*   z     = (const int*)d_in[1];
    const int*   batch = (const int*)d_in[2];
    const int*   ei    = (const int*)d_in[3];
    const float* emb   = (const float*)d_in[4];
    const float* W_in  = (const float*)d_in[5];
    const float* b_in  = (const float*)d_in[6];
    const float* Wq    = (const float*)d_in[7];
    const float* Wk    = (const float*)d_in[8];
    const float* Wv    = (const float*)d_in[9];
    const float* W_rbf = (const float*)d_in[10];
    const float* W_msg = (const float*)d_in[11];
    const float* W_vg  = (const float*)d_in[12];
    const float* W_vs  = (const float*)d_in[13];
    const float* W_nd  = (const float*)d_in[14];
    const float* b_nd  = (const float*)d_in[15];
    const float* gam   = (const float*)d_in[16];
    const float* watt  = (const float*)d_in[17];
    const float* W_out = (const float*)d_in[18];
    const float* b_out = (const float*)d_in[19];

    const int N = in_sizes[0] / 3;      // 20000
    const int E = in_sizes[3] / 2;      // 320000
    const int G = out_size / 512;       // 500

    char* ws = (char*)d_ws;
    size_t o = 0;
    auto alloc = [&](size_t bytes) -> char* {
        o = (o + 255) & ~(size_t)255;
        char* r = ws + o;
        o += bytes;
        return r;
    };
    float4* f_eg   = (float4*)alloc((size_t)E * 16);
    u16*   h16     = (u16*)  alloc((size_t)N * 256 * 2);
    u16*   vf16    = (u16*)  alloc((size_t)N * 3 * 256 * 2);
    u16*   q16     = (u16*)  alloc((size_t)N * 128 * 2);
    u16*   kv8     = (u16*)  alloc((size_t)N * 128 * 2);
    u16*   umb     = (u16*)  alloc((size_t)N * 4 * 128 * 2);
    u16*   b2_16   = (u16*)  alloc((size_t)N * 256 * 2);
    u16*   pool16  = (u16*)  alloc((size_t)G * 256 * 2);
    u32*   f_table = (u32*)  alloc((size_t)4 * 4097 * 128 * 4);
    const size_t LS = 384 * 256 + 2 * (256 * 128) + 2 * (256 * 256);
    const size_t OFF_QKV = 0, OFF_VG = 384 * 256, OFF_MSG = OFF_VG + 256 * 128,
                 OFF_ND = OFF_MSG + 256 * 128, OFF_VS = OFF_ND + 256 * 256;
    const size_t OFF_OUT = LS * 4;
    u16* whi = (u16*)alloc((LS * 4 + 512 * 256) * sizeof(u16));
    u16* wlo = (u16*)alloc((LS * 4 + 512 * 256) * sizeof(u16));
    int*  i_deg   = (int*)alloc((size_t)N * 4);
    int*  i_rowp  = (int*)alloc((size_t)(N + 1) * 4);
    int*  i_cur   = (int*)alloc((size_t)(N + 1) * 4);
    int2* i_perm2 = (int2*)alloc((size_t)E * 8);
    int*  i_gcnt  = (int*)alloc((size_t)G * 4);
    int*  i_gptr  = (int*)alloc((size_t)(G + 1) * 4);

    u16* U16   = umb;                         // [3N,128]
    u16* msg16 = umb + (size_t)3 * N * 128;   // [N,128]

    // ---- weight pre-pass descriptor ----
    TDesc td;
    int idx = 0;
    for (int l = 0; l < 4; ++l) {
        u16* bh = whi + (size_t)l * LS;
        u16* bl = wlo + (size_t)l * LS;
        td.e[idx++] = { Wq   + (size_t)l * 256 * 128, bh + OFF_QKV,             bl + OFF_QKV,             256, 128 };
        td.e[idx++] = { Wk   + (size_t)l * 256 * 128, bh + OFF_QKV + 128 * 256, bl + OFF_QKV + 128 * 256, 256, 128 };
        td.e[idx++] = { Wv   + (size_t)l * 256 * 128, bh + OFF_QKV + 256 * 256, bl + OFF_QKV + 256 * 256, 256, 128 };
        td.e[idx++] = { W_vg + (size_t)l * 128 * 256, bh + OFF_VG,  bl + OFF_VG,  128, 256 };
        td.e[idx++] = { W_msg+ (size_t)l * 128 * 256, bh + OFF_MSG, bl + OFF_MSG, 128, 256 };
        td.e[idx++] = { W_nd + (size_t)l * 256 * 256, bh + OFF_ND,  bl + OFF_ND,  256, 256 };
        td.e[idx++] = { W_vs + (size_t)l * 256 * 256, bh + OFF_VS,  bl + OFF_VS,  256, 256 };
    }
    td.e[idx++] = { W_out, whi + OFF_OUT, wlo + OFF_OUT, 256, 512 };

    // ---- setup ----
    zero2_i32<<<(N + G + 255) / 256, 256, 0, stream>>>(i_deg, N, i_gcnt, G);
    transpose_split<<<dim3(128, 29), 256, 0, stream>>>(td);
    build_rbf_table<<<dim3(4097, 4), 128, 0, stream>>>(W_rbf, f_table);

    setup_edges<<<(E + 255) / 256, 256, 0, stream>>>(ei, batch, pos, E, N,
                                                     i_deg, i_gcnt, f_eg);
    scan2_kernel<<<2, 1024, 0, stream>>>(i_deg, N, i_rowp, i_cur, i_gcnt, G, i_gptr);
    scatter_kernel<<<(E + 255) / 256, 256, 0, stream>>>(ei, i_cur, i_perm2, E);
    init_h_kernel<<<N, 256, 0, stream>>>(z, pos, emb, W_in, b_in, h16);

    const int MB  = (N + 127) / 128;          // 157
    const int MB3 = (3 * N + 127) / 128;      // 469
    const int MBG = (G + 127) / 128;          // 4

    // ---- layers ----
    for (int l = 0; l < 4; ++l) {
        u16* bh = whi + (size_t)l * LS;
        u16* bl = wlo + (size_t)l * LS;
        const float* bnd_l = b_nd + (size_t)l * 256;
        const float* gam_l = gam  + (size_t)l * 256;
        const u32*   tbl_l = f_table + (size_t)l * 4097 * 128;

        // q16/kv8 = h @ [Wq|Wk|Wv]
        mfma_gemm<3,false,false,false,false><<<3 * MB, 256, 0, stream>>>(
            h16, bh + OFF_QKV, nullptr, nullptr, q16, kv8, N, 256, 384, 3);

        edge_attn_kernel<<<N, 128, 0, stream>>>(i_rowp, i_perm2, q16, kv8,
                                                f_eg, tbl_l, msg16, U16);

        // vfeat (+)= U @ W_vgate
        if (l == 0)
            mfma_gemm<1,false,false,false,false><<<2 * MB3, 256, 0, stream>>>(
                U16, bh + OFF_VG, nullptr, nullptr, vf16, nullptr, 3 * N, 128, 256, 2);
        else
            mfma_gemm<2,false,false,false,false><<<2 * MB3, 256, 0, stream>>>(
                U16, bh + OFF_VG, nullptr, nullptr, vf16, nullptr, 3 * N, 128, 256, 2);

        // b2 = gelu(gelu(msg@Wmsg) @ Wnd + bnd)   (fused MLP, b1 in LDS)
        mlp_kernel<<<MB, 512, 0, stream>>>(
            msg16, bh + OFF_MSG, bh + OFF_ND, bl + OFF_ND, bnd_l, b2_16, N);

        // h16 = LN(h16 + b2 + vnorm(vf)@Wvs) * gamma   (fused, inline vnorm)
        vs_ln_kernel<<<MB, 512, 0, stream>>>(
            vf16, bh + OFF_VS, bl + OFF_VS, b2_16, gam_l, h16, N);
    }

    // ---- readout ----
    pool_kernel<<<G, 256, 0, stream>>>(h16, watt, i_gptr, pool16);
    mfma_gemm<0,false,true,false,true><<<4 * MBG, 256, 0, stream>>>(
        pool16, whi + OFF_OUT, wlo + OFF_OUT, b_out, (float*)d_out, nullptr, G, 256, 512, 4);
}

// Round 15
// 786.811 us; speedup vs baseline: 1.0721x; 1.0219x over previous
//
#include <hip/hip_runtime.h>
#include <math.h>

typedef unsigned char  u8;
typedef unsigned short u16;
typedef unsigned int   u32;
typedef __attribute__((ext_vector_type(8))) unsigned short ushort8;
typedef __attribute__((ext_vector_type(4))) unsigned short ushort4v;
typedef __attribute__((ext_vector_type(8))) short short8v;   // 8 bf16 (4 VGPRs)
typedef __attribute__((ext_vector_type(4))) float f32x4;
typedef __attribute__((ext_vector_type(2))) float f32x2;

__device__ __forceinline__ float gelu_f(float x) {
    const float c = 0.7978845608028654f;   // sqrt(2/pi)
    float x3 = x * x * x;
    float t = tanhf(c * (x + 0.044715f * x3));
    return 0.5f * x * (1.0f + t);
}

__device__ __forceinline__ u16 f2b(float f) {
    u32 u = __float_as_uint(f);
    return (u16)((u + 0x7FFFu + ((u >> 16) & 1u)) >> 16);
}
__device__ __forceinline__ float b2f(u16 u) {
    return __uint_as_float(((u32)u) << 16);
}

// fp8 e4m3fn software fallback
__device__ __forceinline__ u32 f2fp8_sw(float f) {
    u32 u = __float_as_uint(f);
    u32 s = (u >> 31) << 7;
    float af = fabsf(f);
    if (af >= 448.0f) return s | 0x7E;
    if (af < 0.015625f) {
        int m = __float2int_rn(af * 512.0f);
        if (m >= 8) return s | 0x08;
        return s | (u32)m;
    }
    u32 a = __float_as_uint(af);
    u32 r = a + 0xFFFFFu + ((a >> 20) & 1u);
    int e8 = (int)(r >> 23) - 120;
    u32 m3 = (r >> 20) & 7u;
    if (e8 >= 16) return s | 0x7E;
    return s | ((u32)e8 << 3) | m3;
}
__device__ __forceinline__ float fp8d_sw(u32 b) {
    u32 lo = b & 0x7Fu;
    u32 nb = (lo << 20) + 0x3C000000u;
    float n = __uint_as_float(nb | ((b & 0x80u) << 24));
    float sub = (float)(b & 7u) * 0.001953125f;
    sub = (b & 0x80u) ? -sub : sub;
    return (lo & 0x78u) ? n : sub;
}
__device__ __forceinline__ u8 f2fp8(float v) {
#if __has_builtin(__builtin_amdgcn_cvt_pk_fp8_f32)
    return (u8)(__builtin_amdgcn_cvt_pk_fp8_f32(v, v, 0, false) & 0xFF);
#else
    return (u8)f2fp8_sw(v);
#endif
}
__device__ __forceinline__ f32x2 kvdec(u32 pair) {
#if __has_builtin(__builtin_amdgcn_cvt_pk_f32_fp8)
    return __builtin_amdgcn_cvt_pk_f32_fp8((int)pair, false);
#else
    f32x2 r;
    r[0] = fp8d_sw(pair & 0xFF);
    r[1] = fp8d_sw((pair >> 8) & 0xFF);
    return r;
#endif
}

__device__ __forceinline__ void split_bf16(float f, u16& h, u16& l) {
    u32 u = __float_as_uint(f);
    u32 r = (u + 0x7FFFu + ((u >> 16) & 1u)) >> 16;
    h = (u16)r;
    float hf = __uint_as_float(r << 16);
    float d = f - hf;
    u32 u2 = __float_as_uint(d);
    l = (u16)((u2 + 0x7FFFu + ((u2 >> 16) & 1u)) >> 16);
}

// bijective XCD-chunked swizzle (m204)
__device__ __forceinline__ int xcd_swz(int orig, int nwg) {
    int q8 = nwg >> 3, r8 = nwg & 7;
    int xcd = orig & 7, ii = orig >> 3;
    return (xcd < r8 ? xcd * (q8 + 1) : r8 * (q8 + 1) + (xcd - r8) * q8) + ii;
}

// ---------------------------------------------------------------------------
__global__ __launch_bounds__(256) void zero2_i32(int* __restrict__ a, int na,
                                                 int* __restrict__ b, int nb) {
    int i = blockIdx.x * 256 + threadIdx.x;
    if (i < na) a[i] = 0;
    else if (i - na < nb) b[i - na] = 0;
}

// ---------------------------------------------------------------------------
// Weight pre-pass: transpose [K][N] f32 -> [N][K] split bf16 hi/lo
// ---------------------------------------------------------------------------
struct TEntry { const float* src; u16* dh; u16* dl; int K; int N; };
struct TDesc  { TEntry e[29]; };

__global__ __launch_bounds__(256) void transpose_split(TDesc desc) {
    __shared__ float tile[32][33];
    TEntry en = desc.e[blockIdx.y];
    int tk = en.K >> 5, tn = en.N >> 5;
    int bx = blockIdx.x;
    if (bx >= tk * tn) return;
    int k0 = (bx % tk) * 32, n0 = (bx / tk) * 32;
    int tx = threadIdx.x & 31, ty = threadIdx.x >> 5;
    #pragma unroll
    for (int yy = 0; yy < 32; yy += 8)
        tile[ty + yy][tx] = en.src[(size_t)(k0 + ty + yy) * en.N + (n0 + tx)];
    __syncthreads();
    #pragma unroll
    for (int yy = 0; yy < 32; yy += 8) {
        int n = n0 + ty + yy, k = k0 + tx;
        float f = tile[tx][ty + yy];
        u16 h, l;
        split_bf16(f, h, l);
        en.dh[(size_t)n * en.K + k] = h;
        en.dl[(size_t)n * en.K + k] = l;
    }
}

// ---------------------------------------------------------------------------
// RBF lookup tables, 4098 bins per layer
// ---------------------------------------------------------------------------
__global__ __launch_bounds__(128) void build_rbf_table(
    const float* __restrict__ W_rbf, float* __restrict__ table)
{
    int k = blockIdx.x, l = blockIdx.y, m = threadIdx.x;
    const float* Wrbf_l = W_rbf + (size_t)l * 32 * 128;
    float* tbl = table + (size_t)l * 4098 * 128;
    const float PI = 3.14159265358979323846f;
    float d = fmaxf((float)k * (6.0f / 4096.0f), 1e-9f);
    float th = d * (PI / 6.0f);
    float s1, c1;
    __sincosf(th, &s1, &c1);
    float env = (d < 6.0f) ? (0.5f * c1 + 0.5f) : 0.0f;
    float invd = 1.0f / d;
    float two_c = 2.0f * c1;
    float sp = 0.f, sc = s1, dot = 0.f;
    #pragma unroll
    for (int r = 0; r < 32; ++r) {
        dot = fmaf(sc, Wrbf_l[r * 128 + m], dot);
        float sn = fmaf(two_c, sc, -sp);
        sp = sc; sc = sn;
    }
    tbl[(size_t)k * 128 + m] = dot * invd * env;
}

// ---------------------------------------------------------------------------
// MFMA GEMM, 1D swizzled grid. A bf16 [M][K]; BH (+BL) transposed bf16 [N][K].
// OMODE: 0 f32 out (ACCUM f32 +=), 1 bf16 out, 2 bf16 out + bf16 accum,
//        3 qkv mixed (Q bf16 / K,V fp8 pairs)
// OMODE 1/2 use an LDS-staged coalesced epilogue (16B/lane stores).
// ---------------------------------------------------------------------------
template<int OMODE, bool ACCUM, bool BIAS, bool DOGELU, bool SPLITB>
__global__ __launch_bounds__(256) void mfma_gemm(
    const u16* __restrict__ A, const u16* __restrict__ BH,
    const u16* __restrict__ BL, const float* __restrict__ bias,
    void* __restrict__ Cv, void* __restrict__ Cv2,
    int Mrows, int K, int Nc, int gx)
{
    constexpr bool STAGE_OUT = (OMODE == 1 || OMODE == 2);
    constexpr int MAIN_B = 128 * 40 * 2 * (SPLITB ? 3 : 2);
    constexpr int OUT_B  = STAGE_OUT ? 128 * 136 * 2 : 0;
    constexpr int SMEM_B = (MAIN_B > OUT_B) ? MAIN_B : OUT_B;
    __shared__ __align__(16) char smem[SMEM_B];
    u16 (*sA)[40]  = (u16(*)[40])smem;
    u16 (*sBh)[40] = (u16(*)[40])(smem + 128 * 40 * 2);
    u16 (*sBl)[40] = (u16(*)[40])(smem + 2 * 128 * 40 * 2);
    u16 (*sOut)[136] = (u16(*)[136])smem;

    const int wg = xcd_swz(blockIdx.x, gridDim.x);
    const int r0 = (wg / gx) * 128, c0 = (wg % gx) * 128;

    const int t = threadIdx.x;
    const int lane = t & 63, wid = t >> 6;
    const int wr = (wid >> 1) * 64, wc = (wid & 1) * 64;

    f32x4 acc[4][4] = {};

    const int srow = t >> 1;
    const int skc  = (t & 1) * 16;

    for (int k0 = 0; k0 < K; k0 += 32) {
        {
            int gr = r0 + srow;
            ushort8 h0, h1;
            if (gr < Mrows) {
                const u16* p = A + (size_t)gr * K + (k0 + skc);
                h0 = *(const ushort8*)p;
                h1 = *(const ushort8*)(p + 8);
            } else {
                #pragma unroll
                for (int j = 0; j < 8; ++j) { h0[j] = 0; h1[j] = 0; }
            }
            *(ushort8*)&sA[srow][skc]     = h0;
            *(ushort8*)&sA[srow][skc + 8] = h1;
        }
        {
            int cg = c0 + srow;
            const u16* ph = BH + (size_t)cg * K + (k0 + skc);
            *(ushort8*)&sBh[srow][skc]     = *(const ushort8*)(ph);
            *(ushort8*)&sBh[srow][skc + 8] = *(const ushort8*)(ph + 8);
            if constexpr (SPLITB) {
                const u16* pl = BL + (size_t)cg * K + (k0 + skc);
                *(ushort8*)&sBl[srow][skc]     = *(const ushort8*)(pl);
                *(ushort8*)&sBl[srow][skc + 8] = *(const ushort8*)(pl + 8);
            }
        }
        __syncthreads();

        const int arow = wr + (lane & 15);
        const int koff = (lane >> 4) * 8;
        short8v ah[4];
        #pragma unroll
        for (int fr = 0; fr < 4; ++fr)
            ah[fr] = *(const short8v*)&sA[arow + fr * 16][koff];
        #pragma unroll
        for (int fc = 0; fc < 4; ++fc) {
            int bcol = wc + fc * 16 + (lane & 15);
            short8v bh = *(const short8v*)&sBh[bcol][koff];
            #pragma unroll
            for (int fr = 0; fr < 4; ++fr)
                acc[fr][fc] = __builtin_amdgcn_mfma_f32_16x16x32_bf16(ah[fr], bh, acc[fr][fc], 0, 0, 0);
            if constexpr (SPLITB) {
                short8v bl = *(const short8v*)&sBl[bcol][koff];
                #pragma unroll
                for (int fr = 0; fr < 4; ++fr)
                    acc[fr][fc] = __builtin_amdgcn_mfma_f32_16x16x32_bf16(ah[fr], bl, acc[fr][fc], 0, 0, 0);
            }
        }
        __syncthreads();
    }

    if constexpr (STAGE_OUT) {
        #pragma unroll
        for (int fr = 0; fr < 4; ++fr) {
            int rbase = wr + fr * 16 + (lane >> 4) * 4;
            #pragma unroll
            for (int fc = 0; fc < 4; ++fc) {
                int col = wc + fc * 16 + (lane & 15);
                #pragma unroll
                for (int reg = 0; reg < 4; ++reg) {
                    float v = acc[fr][fc][reg];
                    if (BIAS)   v += bias[c0 + col];
                    if (DOGELU) v = gelu_f(v);
                    sOut[rbase + reg][col] = f2b(v);
                }
            }
        }
        __syncthreads();
        #pragma unroll
        for (int p = 0; p < 4; ++p) {
            int row = p * 32 + (t >> 3);
            int cch = (t & 7) * 16;
            int gr = r0 + row;
            if (gr < Mrows) {
                u16* gp = (u16*)Cv + (size_t)gr * Nc + c0 + cch;
                ushort8 v0 = *(ushort8*)&sOut[row][cch];
                ushort8 v1 = *(ushort8*)&sOut[row][cch + 8];
                if (OMODE == 2) {
                    ushort8 o0 = *(const ushort8*)gp;
                    ushort8 o1 = *(const ushort8*)(gp + 8);
                    #pragma unroll
                    for (int j = 0; j < 8; ++j) {
                        v0[j] = f2b(b2f(v0[j]) + b2f(o0[j]));
                        v1[j] = f2b(b2f(v1[j]) + b2f(o1[j]));
                    }
                }
                *(ushort8*)gp       = v0;
                *(ushort8*)(gp + 8) = v1;
            }
        }
    } else {
        #pragma unroll
        for (int fr = 0; fr < 4; ++fr) {
            int rbase = r0 + wr + fr * 16 + (lane >> 4) * 4;
            #pragma unroll
            for (int fc = 0; fc < 4; ++fc) {
                int col = c0 + wc + fc * 16 + (lane & 15);
                #pragma unroll
                for (int reg = 0; reg < 4; ++reg) {
                    int gr = rbase + reg;
                    if (gr >= Mrows) continue;
                    float v = acc[fr][fc][reg];
                    if (BIAS)   v += bias[col];
                    if (DOGELU) v = gelu_f(v);
                    if (OMODE == 0) {
                        float* pc = (float*)Cv + (size_t)gr * Nc + col;
                        if (ACCUM) v += *pc;
                        *pc = v;
                    } else {   // OMODE 3: qkv mixed
                        if (col < 128)
                            ((u16*)Cv)[(size_t)gr * 128 + col] = f2b(v);
                        else if (col < 256)
                            ((u8*)Cv2)[(size_t)gr * 256 + (col - 128) * 2] = f2fp8(v);
                        else
                            ((u8*)Cv2)[(size_t)gr * 256 + (col - 256) * 2 + 1] = f2fp8(v);
                    }
                }
            }
        }
    }
}

// ---------------------------------------------------------------------------
// Fused MLP: b2 = gelu(gelu(msg@Wmsg) @ Wnd + bnd).  BM=128, BN=256, 8 waves.
// Phase 1 result b1 lives in LDS only.  Wmsg bf16 [256][128]; Wnd split.
// ---------------------------------------------------------------------------
__global__ __launch_bounds__(512) void mlp_kernel(
    const u16* __restrict__ msg, const u16* __restrict__ Wmsg,
    const u16* __restrict__ WndH, const u16* __restrict__ WndL,
    const float* __restrict__ bnd, u16* __restrict__ b2out, int Mrows)
{
    __shared__ __align__(16) u16 b1[128][264];           // 67.6 KB
    __shared__ __align__(16) char sbuf[256 * 40 * 2 * 2]; // 41 KB staging
    u16 (*sA)[40]   = (u16(*)[40])sbuf;                   // phase1 A
    u16 (*sB)[40]   = (u16(*)[40])(sbuf + 128 * 40 * 2);  // phase1 B
    u16 (*sBh)[40]  = (u16(*)[40])sbuf;                   // phase2 B hi
    u16 (*sBl)[40]  = (u16(*)[40])(sbuf + 256 * 40 * 2);  // phase2 B lo
    u16 (*sOut)[136] = (u16(*)[136])sbuf;                 // epilogue

    const int r0 = xcd_swz(blockIdx.x, gridDim.x) * 128;
    const int t = threadIdx.x;
    const int lane = t & 63, wid = t >> 6;    // 8 waves
    const int wr = (wid >> 2) * 64, wc = (wid & 3) * 64;

    f32x4 acc[4][4] = {};
    const int srowA = t >> 2, skcA = (t & 3) * 8;   // 128 rows x 32k
    const int srowB = t >> 1, skcB = (t & 1) * 16;  // 256 rows x 32k

    // ---- phase 1: b1 = gelu(msg @ Wmsg), K=128 ----
    for (int k0 = 0; k0 < 128; k0 += 32) {
        {
            int gr = r0 + srowA;
            ushort8 h0;
            #pragma unroll
            for (int j = 0; j < 8; ++j) h0[j] = 0;
            if (gr < Mrows) h0 = *(const ushort8*)(msg + (size_t)gr * 128 + k0 + skcA);
            *(ushort8*)&sA[srowA][skcA] = h0;
        }
        {
            const u16* p = Wmsg + (size_t)srowB * 128 + k0 + skcB;
            *(ushort8*)&sB[srowB][skcB]     = *(const ushort8*)p;
            *(ushort8*)&sB[srowB][skcB + 8] = *(const ushort8*)(p + 8);
        }
        __syncthreads();
        const int arow = wr + (lane & 15);
        const int koff = (lane >> 4) * 8;
        short8v ah[4];
        #pragma unroll
        for (int fr = 0; fr < 4; ++fr)
            ah[fr] = *(const short8v*)&sA[arow + fr * 16][koff];
        #pragma unroll
        for (int fc = 0; fc < 4; ++fc) {
            int bcol = wc + fc * 16 + (lane & 15);
            short8v bh = *(const short8v*)&sB[bcol][koff];
            #pragma unroll
            for (int fr = 0; fr < 4; ++fr)
                acc[fr][fc] = __builtin_amdgcn_mfma_f32_16x16x32_bf16(ah[fr], bh, acc[fr][fc], 0, 0, 0);
        }
        __syncthreads();
    }
    // write b1 to LDS (gelu)
    #pragma unroll
    for (int fr = 0; fr < 4; ++fr) {
        int rbase = wr + fr * 16 + (lane >> 4) * 4;
        #pragma unroll
        for (int fc = 0; fc < 4; ++fc) {
            int col = wc + fc * 16 + (lane & 15);
            #pragma unroll
            for (int reg = 0; reg < 4; ++reg) {
                b1[rbase + reg][col] = f2b(gelu_f(acc[fr][fc][reg]));
                acc[fr][fc][reg] = 0.0f;
            }
        }
    }
    __syncthreads();

    // ---- phase 2: b2 = gelu(b1 @ Wnd + bnd), K=256, A from LDS ----
    for (int k0 = 0; k0 < 256; k0 += 32) {
        {
            const u16* ph = WndH + (size_t)srowB * 256 + k0 + skcB;
            const u16* pl = WndL + (size_t)srowB * 256 + k0 + skcB;
            *(ushort8*)&sBh[srowB][skcB]     = *(const ushort8*)ph;
            *(ushort8*)&sBh[srowB][skcB + 8] = *(const ushort8*)(ph + 8);
            *(ushort8*)&sBl[srowB][skcB]     = *(const ushort8*)pl;
            *(ushort8*)&sBl[srowB][skcB + 8] = *(const ushort8*)(pl + 8);
        }
        __syncthreads();
        const int arow = wr + (lane & 15);
        const int koff = (lane >> 4) * 8;
        short8v ah[4];
        #pragma unroll
        for (int fr = 0; fr < 4; ++fr)
            ah[fr] = *(const short8v*)&b1[arow + fr * 16][k0 + koff];
        #pragma unroll
        for (int fc = 0; fc < 4; ++fc) {
            int bcol = wc + fc * 16 + (lane & 15);
            short8v bh = *(const short8v*)&sBh[bcol][koff];
            short8v bl = *(const short8v*)&sBl[bcol][koff];
            #pragma unroll
            for (int fr = 0; fr < 4; ++fr) {
                acc[fr][fc] = __builtin_amdgcn_mfma_f32_16x16x32_bf16(ah[fr], bh, acc[fr][fc], 0, 0, 0);
                acc[fr][fc] = __builtin_amdgcn_mfma_f32_16x16x32_bf16(ah[fr], bl, acc[fr][fc], 0, 0, 0);
            }
        }
        __syncthreads();
    }

    // ---- epilogue: bias + gelu -> coalesced bf16 store ----
    #pragma unroll
    for (int fr = 0; fr < 4; ++fr) {
        int rbase = wr + fr * 16 + (lane >> 4) * 4;
        #pragma unroll
        for (int fc = 0; fc < 4; ++fc) {
            int col = wc + fc * 16 + (lane & 15);
            #pragma unroll
            for (int reg = 0; reg < 4; ++reg)
                sOut[rbase + reg][col] = f2b(gelu_f(acc[fr][fc][reg] + bnd[col]));
        }
    }
    __syncthreads();
    #pragma unroll
    for (int p = 0; p < 2; ++p) {
        int row = p * 64 + (t >> 3);
        int cch = (t & 7) * 16;
        int gr = r0 + row;
        if (gr < Mrows) {
            u16* gp = b2out + (size_t)gr * 256 + cch;
            *(ushort8*)gp       = *(ushort8*)&sOut[row][cch];
            *(ushort8*)(gp + 8) = *(ushort8*)&sOut[row][cch + 8];
        }
    }
}

// ---------------------------------------------------------------------------
// Fused vs-GEMM + LayerNorm, vnorm inline:
// h16 = bf16(LN(h16 + b2 + vnorm(vf)@Wvs) * gamma).  BM=128, 512 threads.
// ---------------------------------------------------------------------------
__global__ __launch_bounds__(512) void vs_ln_kernel(
    const u16* __restrict__ vf, const u16* __restrict__ BH,
    const u16* __restrict__ BL, const u16* __restrict__ b2,
    const float* __restrict__ gamma_l, u16* __restrict__ h16, int Mrows)
{
    __shared__ __align__(16) u16 sA [128][40];
    __shared__ __align__(16) u16 sBh[256][40];
    __shared__ __align__(16) u16 sBl[256][40];
    __shared__ float sSum[128][4];
    __shared__ float sSq [128][4];

    const int r0 = blockIdx.x * 128;
    const int t = threadIdx.x;
    const int lane = t & 63, wid = t >> 6;          // 8 waves
    const int wr = (wid >> 2) * 64, wc = (wid & 3) * 64;

    f32x4 acc[4][4] = {};
    const int K = 256;
    const int srow = t >> 2;          // 0..127
    const int skc  = (t & 3) * 8;     // 0,8,16,24

    for (int k0 = 0; k0 < K; k0 += 32) {
        {
            int gr = r0 + srow;
            ushort8 h0;
            #pragma unroll
            for (int j = 0; j < 8; ++j) h0[j] = 0;
            if (gr < Mrows) {
                const u16* base = vf + ((size_t)gr * 3) * 256 + k0 + skc;
                ushort8 v0 = *(const ushort8*)(base);
                ushort8 v1 = *(const ushort8*)(base + 256);
                ushort8 v2 = *(const ushort8*)(base + 512);
                #pragma unroll
                for (int j = 0; j < 8; ++j) {
                    float a = b2f(v0[j]), b = b2f(v1[j]), c = b2f(v2[j]);
                    h0[j] = f2b(sqrtf(a * a + b * b + c * c + 1e-8f));
                }
            }
            *(ushort8*)&sA[srow][skc] = h0;
        }
        {
            *(ushort8*)&sBh[srow][skc]       = *(const ushort8*)(BH + (size_t)srow * K + k0 + skc);
            *(ushort8*)&sBh[srow + 128][skc] = *(const ushort8*)(BH + (size_t)(srow + 128) * K + k0 + skc);
            *(ushort8*)&sBl[srow][skc]       = *(const ushort8*)(BL + (size_t)srow * K + k0 + skc);
            *(ushort8*)&sBl[srow + 128][skc] = *(const ushort8*)(BL + (size_t)(srow + 128) * K + k0 + skc);
        }
        __syncthreads();

        const int arow = wr + (lane & 15);
        const int koff = (lane >> 4) * 8;
        short8v ah[4];
        #pragma unroll
        for (int fr = 0; fr < 4; ++fr)
            ah[fr] = *(const short8v*)&sA[arow + fr * 16][koff];
        #pragma unroll
        for (int fc = 0; fc < 4; ++fc) {
            int bcol = wc + fc * 16 + (lane & 15);
            short8v bh = *(const short8v*)&sBh[bcol][koff];
            short8v bl = *(const short8v*)&sBl[bcol][koff];
            #pragma unroll
            for (int fr = 0; fr < 4; ++fr) {
                acc[fr][fc] = __builtin_amdgcn_mfma_f32_16x16x32_bf16(ah[fr], bh, acc[fr][fc], 0, 0, 0);
                acc[fr][fc] = __builtin_amdgcn_mfma_f32_16x16x32_bf16(ah[fr], bl, acc[fr][fc], 0, 0, 0);
            }
        }
        __syncthreads();
    }

    // epilogue: x = h_old + b2 + vsout; row stats, LN, write
    float psum[4][4] = {}, psq[4][4] = {};
    #pragma unroll
    for (int fr = 0; fr < 4; ++fr) {
        #pragma unroll
        for (int fc = 0; fc < 4; ++fc) {
            int col = wc + fc * 16 + (lane & 15);
            #pragma unroll
            for (int reg = 0; reg < 4; ++reg) {
                int gr = r0 + wr + fr * 16 + (lane >> 4) * 4 + reg;
                float x = 0.f;
                if (gr < Mrows) {
                    size_t ix = (size_t)gr * 256 + col;
                    x = acc[fr][fc][reg] + b2f(b2[ix]) + b2f(h16[ix]);
                }
                acc[fr][fc][reg] = x;
                psum[fr][reg] += x;
                psq[fr][reg]  = fmaf(x, x, psq[fr][reg]);
            }
        }
    }
    #pragma unroll
    for (int fr = 0; fr < 4; ++fr) {
        #pragma unroll
        for (int reg = 0; reg < 4; ++reg) {
            float s = psum[fr][reg], sq = psq[fr][reg];
            #pragma unroll
            for (int off = 8; off; off >>= 1) {
                s  += __shfl_xor(s, off);
                sq += __shfl_xor(sq, off);
            }
            psum[fr][reg] = s; psq[fr][reg] = sq;
        }
    }
    if ((lane & 15) == 0) {
        int qg = lane >> 4;
        #pragma unroll
        for (int fr = 0; fr < 4; ++fr) {
            #pragma unroll
            for (int reg = 0; reg < 4; ++reg) {
                int row = wr + fr * 16 + qg * 4 + reg;
                sSum[row][wc >> 6] = psum[fr][reg];
                sSq [row][wc >> 6] = psq[fr][reg];
            }
        }
    }
    __syncthreads();
    #pragma unroll
    for (int fr = 0; fr < 4; ++fr) {
        #pragma unroll
        for (int reg = 0; reg < 4; ++reg) {
            int row = wr + fr * 16 + (lane >> 4) * 4 + reg;
            int gr = r0 + row;
            if (gr >= Mrows) continue;
            float S = sSum[row][0] + sSum[row][1] + sSum[row][2] + sSum[row][3];
            float Q = sSq[row][0] + sSq[row][1] + sSq[row][2] + sSq[row][3];
            float mu = S * (1.0f / 256.0f);
            float var = fmaxf(Q * (1.0f / 256.0f) - mu * mu, 0.0f);
            float rs = rsqrtf(var + 1e-5f);
            #pragma unroll
            for (int fc = 0; fc < 4; ++fc) {
                int col = wc + fc * 16 + (lane & 15);
                float y = (acc[fr][fc][reg] - mu) * rs * gamma_l[col];
                h16[(size_t)gr * 256 + col] = f2b(y);
            }
        }
    }
}

// ---------------------------------------------------------------------------
// Setup: per-edge degree hist + geometry, per-node graph hist (one kernel)
// ---------------------------------------------------------------------------
__global__ __launch_bounds__(256) void setup_edges(
    const int* __restrict__ ei, const int* __restrict__ batch,
    const float* __restrict__ pos, int E_, int Nn,
    int* __restrict__ deg, int* __restrict__ gcnt, float4* __restrict__ eg)
{
    int x = blockIdx.x * 256 + threadIdx.x;
    if (x < E_) {
        int s = ei[x], dn = ei[E_ + x];
        atomicAdd(&deg[dn], 1);
        float dx = pos[s * 3 + 0] - pos[dn * 3 + 0];
        float dy = pos[s * 3 + 1] - pos[dn * 3 + 1];
        float dz = pos[s * 3 + 2] - pos[dn * 3 + 2];
        float d = sqrtf(dx * dx + dy * dy + dz * dz + 1e-12f);
        float invd = 1.0f / d;
        eg[x] = make_float4(dx * invd, dy * invd, dz * invd, d);
    }
    if (x < Nn) atomicAdd(&gcnt[batch[x]], 1);
}

// two scans in one launch: block 0 -> (cntA,nA), block 1 -> (cntB,nB)
__global__ __launch_bounds__(1024) void scan2_kernel(
    const int* __restrict__ cntA, int nA, int* __restrict__ outA, int* __restrict__ curA,
    const int* __restrict__ cntB, int nB, int* __restrict__ outB)
{
    __shared__ int part[1024];
    const int* cnt = (blockIdx.x == 0) ? cntA : cntB;
    int n          = (blockIdx.x == 0) ? nA : nB;
    int* out       = (blockIdx.x == 0) ? outA : outB;
    int* cursor    = (blockIdx.x == 0) ? curA : (int*)nullptr;
    int t = threadIdx.x;
    int chunk = (n + 1023) / 1024;
    int base = t * chunk;
    int s = 0;
    for (int k = 0; k < chunk; ++k) { int i = base + k; if (i < n) s += cnt[i]; }
    part[t] = s;
    __syncthreads();
    for (int off = 1; off < 1024; off <<= 1) {
        int u = (t >= off) ? part[t - off] : 0;
        __syncthreads();
        part[t] += u;
        __syncthreads();
    }
    int run = part[t] - s;
    for (int k = 0; k < chunk; ++k) {
        int i = base + k;
        if (i < n) {
            out[i] = run;
            if (cursor) cursor[i] = run;
            run += cnt[i];
        }
    }
    if (t == 1023) out[n] = part[1023];
}

// perm payload: (edge id, src node)
__global__ void scatter_kernel(const int* __restrict__ ei, int* __restrict__ cursor,
                               int2* __restrict__ perm2, int E_) {
    int e = blockIdx.x * 256 + threadIdx.x;
    if (e < E_) {
        int p = atomicAdd(&cursor[ei[E_ + e]], 1);
        perm2[p] = make_int2(e, ei[e]);
    }
}

// ---------------------------------------------------------------------------
// h init -> bf16
// ---------------------------------------------------------------------------
__global__ __launch_bounds__(256) void init_h_kernel(
    const int* __restrict__ z, const float* __restrict__ pos,
    const float* __restrict__ emb, const float* __restrict__ W_in,
    const float* __restrict__ b_in, u16* __restrict__ h16)
{
    int i = blockIdx.x, d = threadIdx.x;
    float acc = b_in[d];
    int zi = z[i];
    #pragma unroll 8
    for (int k = 0; k < 32; ++k)
        acc += emb[zi * 32 + k] * W_in[k * 256 + d];
    #pragma unroll
    for (int x = 0; x < 3; ++x)
        acc += pos[i * 3 + x] * W_in[(32 + x) * 256 + d];
    h16[(size_t)i * 256 + d] = f2b(acc);
}

// ---------------------------------------------------------------------------
// Per-dst-node edge attention, online softmax, 8 edges/iter.
// ---------------------------------------------------------------------------
__global__ __launch_bounds__(128) void edge_attn_kernel(
    const int* __restrict__ rowptr, const int2* __restrict__ perm2,
    const u16* __restrict__ q16, const u16* __restrict__ kv8,
    const float4* __restrict__ eg, const float* __restrict__ table_l,
    u16* __restrict__ msg, u16* __restrict__ U)
{
    int m = threadIdx.x;
    int i = blockIdx.x;

    int p0 = rowptr[i], p1 = rowptr[i + 1];
    float q = b2f(q16[(size_t)i * 128 + m]);
    float Mx = -1e30f, S = 0.f, am = 0.f, a0 = 0.f, a1 = 0.f, a2 = 0.f;
    const float iscale = 0.1767766952966369f;   // 1/sqrt(32)

    for (int p = p0; p < p1; p += 8) {
        int rem = p1 - p;
        int ee[8], jj[8];
        #pragma unroll
        for (int u = 0; u < 8; ++u) {
            int pp = p + (u < rem ? u : 0);
            int2 pe = perm2[pp];
            ee[u] = __builtin_amdgcn_readfirstlane(pe.x);
            jj[u] = __builtin_amdgcn_readfirstlane(pe.y);
        }
        u32 kv[8];
        float4 g[8];
        #pragma unroll
        for (int u = 0; u < 8; ++u) {
            kv[u] = kv8[(size_t)jj[u] * 128 + m];
            g[u]  = eg[ee[u]];
        }
        float lg[8], vd[8];
        #pragma unroll
        for (int u = 0; u < 8; ++u) {
            f32x2 c = kvdec(kv[u]);
            vd[u] = c[1];
            float pr = q * c[0];
            #pragma unroll
            for (int off = 16; off; off >>= 1) pr += __shfl_xor(pr, off);
            lg[u] = pr * iscale;
        }
        float ew[8];
        #pragma unroll
        for (int u = 0; u < 8; ++u) {
            float x = fminf(g[u].w * (4096.0f / 6.0f), 4096.0f);
            int b = (int)x;
            float tf = x - (float)b;
            float f0 = table_l[(size_t)b * 128 + m];
            float f1 = table_l[(size_t)(b + 1) * 128 + m];
            ew[u] = fmaf(tf, f1 - f0, f0);
        }
        float Mb = Mx;
        #pragma unroll
        for (int u = 0; u < 8; ++u) Mb = fmaxf(Mb, lg[u]);
        float sc = __expf(Mx - Mb);
        float ws = 0.f, wvs = 0.f, wx = 0.f, wy = 0.f, wz = 0.f;
        #pragma unroll
        for (int u = 0; u < 8; ++u) {
            float w = (u < rem) ? __expf(lg[u] - Mb) : 0.f;
            float wv = w * vd[u] * ew[u];
            ws  += w;
            wvs += wv;
            wx = fmaf(wv, g[u].x, wx);
            wy = fmaf(wv, g[u].y, wy);
            wz = fmaf(wv, g[u].z, wz);
        }
        S  = S  * sc + ws;
        am = am * sc + wvs;
        a0 = a0 * sc + wx;
        a1 = a1 * sc + wy;
        a2 = a2 * sc + wz;
        Mx = Mb;
    }
    float inv = 1.0f / (S + 1e-12f);
    msg[(size_t)i * 128 + m] = f2b(am * inv);
    U[((size_t)i * 3 + 0) * 128 + m] = f2b(a0 * inv);
    U[((size_t)i * 3 + 1) * 128 + m] = f2b(a1 * inv);
    U[((size_t)i * 3 + 2) * 128 + m] = f2b(a2 * inv);
}

// ---------------------------------------------------------------------------
// Graph pooling, wave-parallel (block = graph)
// ---------------------------------------------------------------------------
__global__ __launch_bounds__(256) void pool_kernel(
    const u16* __restrict__ h16, const float* __restrict__ w_att,
    const int* __restrict__ gptr, u16* __restrict__ pooled)
{
    __shared__ float sM[4], sS[4];
    __shared__ float sAcc[4][256];
    int g = blockIdx.x;
    int t = threadIdx.x, w = t >> 6, lane = t & 63;
    int c0 = lane * 4;
    int n0 = gptr[g], n1 = gptr[g + 1];
    float4 wa = *(const float4*)(w_att + c0);
    float M = -1e30f, S = 0.f, a0 = 0.f, a1 = 0.f, a2 = 0.f, a3 = 0.f;
    for (int i = n0 + w; i < n1; i += 4) {
        ushort4v hv = *(const ushort4v*)(h16 + (size_t)i * 256 + c0);
        float h0 = b2f(hv[0]), h1 = b2f(hv[1]), h2 = b2f(hv[2]), h3 = b2f(hv[3]);
        float p = h0 * wa.x + h1 * wa.y + h2 * wa.z + h3 * wa.w;
        #pragma unroll
        for (int off = 32; off; off >>= 1) p += __shfl_xor(p, off);
        float nM = fmaxf(M, p);
        float sc = __expf(M - nM), wg = __expf(p - nM);
        S = S * sc + wg;
        a0 = a0 * sc + wg * h0;
        a1 = a1 * sc + wg * h1;
        a2 = a2 * sc + wg * h2;
        a3 = a3 * sc + wg * h3;
        M = nM;
    }
    sAcc[w][c0 + 0] = a0; sAcc[w][c0 + 1] = a1;
    sAcc[w][c0 + 2] = a2; sAcc[w][c0 + 3] = a3;
    if (lane == 0) { sM[w] = M; sS[w] = S; }
    __syncthreads();
    if (w == 0) {
        float Mg = fmaxf(fmaxf(sM[0], sM[1]), fmaxf(sM[2], sM[3]));
        float e0 = __expf(sM[0] - Mg), e1 = __expf(sM[1] - Mg);
        float e2 = __expf(sM[2] - Mg), e3 = __expf(sM[3] - Mg);
        float St = sS[0] * e0 + sS[1] * e1 + sS[2] * e2 + sS[3] * e3;
        float inv = 1.0f / (St + 1e-12f);
        #pragma unroll
        for (int c = 0; c < 4; ++c) {
            float v = sAcc[0][c0 + c] * e0 + sAcc[1][c0 + c] * e1
                    + sAcc[2][c0 + c] * e2 + sAcc[3][c0 + c] * e3;
            pooled[(size_t)g * 256 + c0 + c] = f2b(v * inv);
        }
    }
}

// ---------------------------------------------------------------------------
extern "C" void kernel_launch(void* const* d_in, const int* in_sizes, int n_in,
                              void* d_out, int out_size, void* d_ws, size_t ws_size,
                              hipStream_t stream)
{
    const float* pos   = (const float*)d_in[0];
    const int*   z     = (const int*)d_in[1];
    const int*   batch = (const int*)d_in[2];
    const int*   ei    = (const int*)d_in[3];
    const float* emb   = (const float*)d_in[4];
    const float* W_in  = (const float*)d_in[5];
    const float* b_in  = (const float*)d_in[6];
    const float* Wq    = (const float*)d_in[7];
    const float* Wk    = (const float*)d_in[8];
    const float* Wv    = (const float*)d_in[9];
    const float* W_rbf = (const float*)d_in[10];
    const float* W_msg = (const float*)d_in[11];
    const float* W_vg  = (const float*)d_in[12];
    const float* W_vs  = (const float*)d_in[13];
    const float* W_nd  = (const float*)d_in[14];
    const float* b_nd  = (const float*)d_in[15];
    const float* gam   = (const float*)d_in[16];
    const float* watt  = (const float*)d_in[17];
    const float* W_out = (const float*)d_in[18];
    const float* b_out = (const float*)d_in[19];

    const int N = in_sizes[0] / 3;      // 20000
    const int E = in_sizes[3] / 2;      // 320000
    const int G = out_size / 512;       // 500

    char* ws = (char*)d_ws;
    size_t o = 0;
    auto alloc = [&](size_t bytes) -> char* {
        o = (o + 255) & ~(size_t)255;
        char* r = ws + o;
        o += bytes;
        return r;
    };
    float4* f_eg   = (float4*)alloc((size_t)E * 16);
    u16*   h16     = (u16*)  alloc((size_t)N * 256 * 2);
    u16*   vf16    = (u16*)  alloc((size_t)N * 3 * 256 * 2);
    u16*   q16     = (u16*)  alloc((size_t)N * 128 * 2);
    u16*   kv8     = (u16*)  alloc((size_t)N * 128 * 2);
    u16*   umb     = (u16*)  alloc((size_t)N * 4 * 128 * 2);
    u16*   b2_16   = (u16*)  alloc((size_t)N * 256 * 2);
    u16*   pool16  = (u16*)  alloc((size_t)G * 256 * 2);
    float* f_table = (float*)alloc((size_t)4 * 4098 * 128 * 4);
    const size_t LS = 384 * 256 + 2 * (256 * 128) + 2 * (256 * 256);
    const size_t OFF_QKV = 0, OFF_VG = 384 * 256, OFF_MSG = OFF_VG + 256 * 128,
                 OFF_ND = OFF_MSG + 256 * 128, OFF_VS = OFF_ND + 256 * 256;
    const size_t OFF_OUT = LS * 4;
    u16* whi = (u16*)alloc((LS * 4 + 512 * 256) * sizeof(u16));
    u16* wlo = (u16*)alloc((LS * 4 + 512 * 256) * sizeof(u16));
    int*  i_deg   = (int*)alloc((size_t)N * 4);
    int*  i_rowp  = (int*)alloc((size_t)(N + 1) * 4);
    int*  i_cur   = (int*)alloc((size_t)(N + 1) * 4);
    int2* i_perm2 = (int2*)alloc((size_t)E * 8);
    int*  i_gcnt  = (int*)alloc((size_t)G * 4);
    int*  i_gptr  = (int*)alloc((size_t)(G + 1) * 4);

    u16* U16   = umb;                         // [3N,128]
    u16* msg16 = umb + (size_t)3 * N * 128;   // [N,128]

    // ---- weight pre-pass descriptor ----
    TDesc td;
    int idx = 0;
    for (int l = 0; l < 4; ++l) {
        u16* bh = whi + (size_t)l * LS;
        u16* bl = wlo + (size_t)l * LS;
        td.e[idx++] = { Wq   + (size_t)l * 256 * 128, bh + OFF_QKV,             bl + OFF_QKV,             256, 128 };
        td.e[idx++] = { Wk   + (size_t)l * 256 * 128, bh + OFF_QKV + 128 * 256, bl + OFF_QKV + 128 * 256, 256, 128 };
        td.e[idx++] = { Wv   + (size_t)l * 256 * 128, bh + OFF_QKV + 256 * 256, bl + OFF_QKV + 256 * 256, 256, 128 };
        td.e[idx++] = { W_vg + (size_t)l * 128 * 256, bh + OFF_VG,  bl + OFF_VG,  128, 256 };
        td.e[idx++] = { W_msg+ (size_t)l * 128 * 256, bh + OFF_MSG, bl + OFF_MSG, 128, 256 };
        td.e[idx++] = { W_nd + (size_t)l * 256 * 256, bh + OFF_ND,  bl + OFF_ND,  256, 256 };
        td.e[idx++] = { W_vs + (size_t)l * 256 * 256, bh + OFF_VS,  bl + OFF_VS,  256, 256 };
    }
    td.e[idx++] = { W_out, whi + OFF_OUT, wlo + OFF_OUT, 256, 512 };

    // ---- setup ----
    zero2_i32<<<(N + G + 255) / 256, 256, 0, stream>>>(i_deg, N, i_gcnt, G);
    transpose_split<<<dim3(128, 29), 256, 0, stream>>>(td);
    build_rbf_table<<<dim3(4098, 4), 128, 0, stream>>>(W_rbf, f_table);

    setup_edges<<<(E + 255) / 256, 256, 0, stream>>>(ei, batch, pos, E, N,
                                                     i_deg, i_gcnt, f_eg);
    scan2_kernel<<<2, 1024, 0, stream>>>(i_deg, N, i_rowp, i_cur, i_gcnt, G, i_gptr);
    scatter_kernel<<<(E + 255) / 256, 256, 0, stream>>>(ei, i_cur, i_perm2, E);
    init_h_kernel<<<N, 256, 0, stream>>>(z, pos, emb, W_in, b_in, h16);

    const int MB  = (N + 127) / 128;          // 157
    const int MB3 = (3 * N + 127) / 128;      // 469
    const int MBG = (G + 127) / 128;          // 4

    // ---- layers ----
    for (int l = 0; l < 4; ++l) {
        u16* bh = whi + (size_t)l * LS;
        u16* bl = wlo + (size_t)l * LS;
        const float* bnd_l = b_nd + (size_t)l * 256;
        const float* gam_l = gam  + (size_t)l * 256;
        const float* tbl_l = f_table + (size_t)l * 4098 * 128;

        // q16/kv8 = h @ [Wq|Wk|Wv]
        mfma_gemm<3,false,false,false,false><<<3 * MB, 256, 0, stream>>>(
            h16, bh + OFF_QKV, nullptr, nullptr, q16, kv8, N, 256, 384, 3);

        edge_attn_kernel<<<N, 128, 0, stream>>>(i_rowp, i_perm2, q16, kv8,
                                                f_eg, tbl_l, msg16, U16);

        // vfeat (+)= U @ W_vgate   (staged coalesced epilogue)
        if (l == 0)
            mfma_gemm<1,false,false,false,false><<<2 * MB3, 256, 0, stream>>>(
                U16, bh + OFF_VG, nullptr, nullptr, vf16, nullptr, 3 * N, 128, 256, 2);
        else
            mfma_gemm<2,false,false,false,false><<<2 * MB3, 256, 0, stream>>>(
                U16, bh + OFF_VG, nullptr, nullptr, vf16, nullptr, 3 * N, 128, 256, 2);

        // b2 = gelu(gelu(msg@Wmsg) @ Wnd + bnd)   (fused MLP, b1 in LDS)
        mlp_kernel<<<MB, 512, 0, stream>>>(
            msg16, bh + OFF_MSG, bh + OFF_ND, bl + OFF_ND, bnd_l, b2_16, N);

        // h16 = LN(h16 + b2 + vnorm(vf)@Wvs) * gamma   (fused, inline vnorm)
        vs_ln_kernel<<<MB, 512, 0, stream>>>(
            vf16, bh + OFF_VS, bl + OFF_VS, b2_16, gam_l, h16, N);
    }

    // ---- readout ----
    pool_kernel<<<G, 256, 0, stream>>>(h16, watt, i_gptr, pool16);
    mfma_gemm<0,false,true,false,true><<<4 * MBG, 256, 0, stream>>>(
        pool16, whi + OFF_OUT, wlo + OFF_OUT, b_out, (float*)d_out, nullptr, G, 256, 512, 4);
}